// Round 19
// baseline (1555.254 us; speedup 1.0000x reference)
//
#include <hip/hip_runtime.h>
#include <hip/hip_bf16.h>
#include <stdint.h>

#define N_NODES 100000
#define N_REL   16
#define N_EDGE  50000
#define DIM     500
#define TOT_E   (N_REL * N_EDGE)      // 800,000
#define CNT_N   (N_REL * N_NODES)     // 1,600,000

// ws layout (8/16B-aligned):
#define INV_OFF    0ull
#define DEG_OFF    6400000ull
#define ROW_OFF    6800000ull
#define SCANP_OFF  7201000ull
#define CURS_OFF   7210000ull
#define ELIST_OFF  7610000ull     // 800k uint2
#define WB1_OFF    14020000ull
#define WB2_OFF    14550000ull
#define H1_OFF     15080000ull    // 50M bf16 h1 -> ends 115,080,000
#define WEXP1_OFF  115080000ull   // 16*5*500 f32 = 160,000 B
#define WEXP2_OFF  115240000ull   // -> end 115,400,000

typedef __attribute__((ext_vector_type(8))) short bf16x8;
typedef __attribute__((ext_vector_type(4))) float f32x4;

// ---------------- threefry2x32, partitionable-mode mask (R8-verified) ----------------
__device__ __forceinline__ uint32_t rotl32(uint32_t x, int d) {
    return (x << d) | (x >> (32 - d));
}
__device__ __forceinline__ bool edge_keep(uint32_t j) {
    uint32_t x0 = 0u, x1 = j;
    const uint32_t ks0 = 0u, ks1 = 42u, ks2 = 0u ^ 42u ^ 0x1BD11BDAu;
    const int RA[4] = {13, 15, 26, 6};
    const int RB[4] = {17, 29, 16, 24};
    x0 += ks0; x1 += ks1;
#pragma unroll
    for (int i = 0; i < 4; i++) { x0 += x1; x1 = rotl32(x1, RA[i]); x1 ^= x0; }
    x0 += ks1; x1 += ks2 + 1u;
#pragma unroll
    for (int i = 0; i < 4; i++) { x0 += x1; x1 = rotl32(x1, RB[i]); x1 ^= x0; }
    x0 += ks2; x1 += ks0 + 2u;
#pragma unroll
    for (int i = 0; i < 4; i++) { x0 += x1; x1 = rotl32(x1, RA[i]); x1 ^= x0; }
    x0 += ks0; x1 += ks1 + 3u;
#pragma unroll
    for (int i = 0; i < 4; i++) { x0 += x1; x1 = rotl32(x1, RB[i]); x1 ^= x0; }
    x0 += ks1; x1 += ks2 + 4u;
#pragma unroll
    for (int i = 0; i < 4; i++) { x0 += x1; x1 = rotl32(x1, RA[i]); x1 ^= x0; }
    x0 += ks2; x1 += ks0 + 5u;
    return ((x0 ^ x1) >> 31) == 0u;
}

__device__ __forceinline__ uint16_t f2bf(float f) {
    uint32_t u = __float_as_uint(f);
    u += 0x7FFFu + ((u >> 16) & 1u);
    return (uint16_t)(u >> 16);
}
__device__ __forceinline__ float bf2f(uint16_t v) {
    return __uint_as_float((uint32_t)v << 16);
}

// ---------------- CSR build ----------------
__global__ __launch_bounds__(256) void zero_kernel(uint32_t* __restrict__ p, int n) {
    int t = blockIdx.x * blockDim.x + threadIdx.x;
    if (t < n) p[t] = 0u;
}

__global__ __launch_bounds__(256) void count_kernel(
        const int* __restrict__ eidx, uint32_t* __restrict__ cnt,
        uint32_t* __restrict__ deg) {
    int tid = blockIdx.x * blockDim.x + threadIdx.x;
    if (tid >= TOT_E) return;
    if (edge_keep((uint32_t)tid)) {
        int r = tid / N_EDGE;
        int e = tid - r * N_EDGE;
        int dst = eidx[(r * 2 + 1) * N_EDGE + e];
        atomicAdd(&cnt[r * N_NODES + dst], 1u);
        atomicAdd(&deg[dst], 1u);
    }
}

__global__ __launch_bounds__(256) void inv_kernel(uint32_t* __restrict__ cnt_u,
                                                  float* __restrict__ inv) {
    int t = blockIdx.x * blockDim.x + threadIdx.x;
    if (t < CNT_N) {
        float c = (float)cnt_u[t];
        inv[t] = 1.0f / fmaxf(c, 1.0f);
    }
}

__global__ __launch_bounds__(256) void scan1_kernel(
        const uint32_t* __restrict__ deg, uint32_t* __restrict__ rowptr,
        uint32_t* __restrict__ scanp) {
    __shared__ uint32_t sh[256];
    int b = blockIdx.x, t = threadIdx.x;
    int base = b * 1024 + t * 4;
    uint32_t x[4];
#pragma unroll
    for (int i = 0; i < 4; i++) x[i] = (base + i < N_NODES) ? deg[base + i] : 0u;
    uint32_t s = x[0] + x[1] + x[2] + x[3];
    sh[t] = s; __syncthreads();
    for (int off = 1; off < 256; off <<= 1) {
        uint32_t v = (t >= off) ? sh[t - off] : 0u;
        __syncthreads();
        sh[t] += v;
        __syncthreads();
    }
    uint32_t run = sh[t] - s;
    if (t == 255) scanp[b] = sh[255];
#pragma unroll
    for (int i = 0; i < 4; i++) {
        if (base + i < N_NODES) rowptr[base + i] = run;
        run += x[i];
    }
}

__global__ __launch_bounds__(128) void scan2_kernel(
        uint32_t* __restrict__ scanp, uint32_t* __restrict__ rowptr, int nb) {
    __shared__ uint32_t sh[128];
    int t = threadIdx.x;
    uint32_t v = (t < nb) ? scanp[t] : 0u;
    sh[t] = v; __syncthreads();
    for (int off = 1; off < 128; off <<= 1) {
        uint32_t u = (t >= off) ? sh[t - off] : 0u;
        __syncthreads();
        sh[t] += u;
        __syncthreads();
    }
    if (t < nb) scanp[t] = sh[t] - v;
    if (t == 127) rowptr[N_NODES] = sh[127];
}

__global__ __launch_bounds__(256) void scan3_kernel(
        uint32_t* __restrict__ rowptr, const uint32_t* __restrict__ scanp,
        uint32_t* __restrict__ curs) {
    int b = blockIdx.x, t = threadIdx.x;
    int base = b * 1024 + t * 4;
    uint32_t off = scanp[b];
#pragma unroll
    for (int i = 0; i < 4; i++) {
        int idx = base + i;
        if (idx < N_NODES) {
            uint32_t v = rowptr[idx] + off;
            rowptr[idx] = v;
            curs[idx] = v;
        }
    }
}

__global__ __launch_bounds__(256) void scatter_kernel(
        const int* __restrict__ eidx, const float* __restrict__ inv,
        uint32_t* __restrict__ curs, uint2* __restrict__ elist2) {
    int tid = blockIdx.x * blockDim.x + threadIdx.x;
    if (tid >= TOT_E) return;
    if (edge_keep((uint32_t)tid)) {
        int r = tid / N_EDGE;
        int e = tid - r * N_EDGE;
        int src = eidx[(r * 2 + 0) * N_EDGE + e];
        int dst = eidx[(r * 2 + 1) * N_EDGE + e];
        uint32_t pos = atomicAdd(&curs[dst], 1u);
        uint2 rec;
        rec.x = (uint32_t)src | ((uint32_t)r << 20);
        rec.y = __float_as_uint(inv[r * N_NODES + dst]);
        elist2[pos] = rec;
    }
}

// ---------------- weight conversions ----------------
__global__ __launch_bounds__(256) void conv_w_kernel(
        const float* __restrict__ W, uint16_t* __restrict__ Bt) {
    int idx = blockIdx.x * 256 + threadIdx.x;
    int n = idx >> 9, k = idx & 511;
    float v = (n < DIM && k < DIM) ? W[k * DIM + n] : 0.f;
    Bt[idx] = f2bf(v);
}

// wexp[r][i][j] = w_rel[r][j/5][i][j%5]  (16 x 5 x 500 f32): lane-j coalesced
__global__ __launch_bounds__(256) void conv_wexp_kernel(
        const float* __restrict__ W, float* __restrict__ wexp) {
    int idx = blockIdx.x * 256 + threadIdx.x;
    if (idx >= N_REL * 5 * DIM) return;
    int r = idx / (5 * DIM);
    int rem = idx - r * 5 * DIM;
    int i = rem / DIM;
    int j = rem - i * DIM;
    wexp[idx] = W[r * 2500 + (j / 5) * 25 + i * 5 + (j % 5)];
}

// ---------------- MFMA bf16 GEMM 128x128 + fused {msgsum add, ReLU, store} ----------------
// AF32: stage A from f32 with in-stage bf16 convert (kills conv_x).
// OUTBF16: write bf16 (h1) else f32 (final out).
// msg/outf may alias element-wise (same thread reads msg[i] then writes out[i]).
template <bool AF32, bool OUTBF16>
__global__ __launch_bounds__(256) void gemm_fused_kernel(
        const void* __restrict__ A, const uint16_t* __restrict__ Bt,
        const float* msg, float* outf, uint16_t* houtf, int M) {
    __shared__ uint16_t As[128][72];
    __shared__ uint16_t Bs[128][72];
    int m0 = blockIdx.x * 128;
    int n0 = blockIdx.y * 128;
    int t = threadIdx.x;
    int wave = t >> 6, lane = t & 63;
    int wm = wave >> 1, wn = wave & 1;
    f32x4 acc[4][4] = {};

    for (int k0 = 0; k0 < 512; k0 += 64) {
#pragma unroll
        for (int i = 0; i < 4; i++) {
            int c = t * 4 + i;             // 0..1023
            int row = c >> 3;              // 0..127
            int col = (c & 7) * 8;         // 0..56
            int gm = m0 + row, gk = k0 + col;
            uint16_t* dst = &As[row][col];
            if constexpr (AF32) {
                const float* Af = (const float*)A;
                if (gm < M && gk + 7 < DIM) {
                    float4 p0 = *(const float4*)&Af[(size_t)gm * DIM + gk];
                    float4 p1 = *(const float4*)&Af[(size_t)gm * DIM + gk + 4];
                    dst[0] = f2bf(p0.x); dst[1] = f2bf(p0.y);
                    dst[2] = f2bf(p0.z); dst[3] = f2bf(p0.w);
                    dst[4] = f2bf(p1.x); dst[5] = f2bf(p1.y);
                    dst[6] = f2bf(p1.z); dst[7] = f2bf(p1.w);
                } else {
#pragma unroll
                    for (int q = 0; q < 8; q++)
                        dst[q] = (gm < M && gk + q < DIM)
                                     ? f2bf(Af[(size_t)gm * DIM + gk + q]) : (uint16_t)0;
                }
            } else {
                const uint16_t* Ab = (const uint16_t*)A;
                if (gm < M && gk + 7 < DIM) {
                    *(bf16x8*)dst = *(const bf16x8*)&Ab[(size_t)gm * DIM + gk];
                } else {
#pragma unroll
                    for (int q = 0; q < 8; q++)
                        dst[q] = (gm < M && gk + q < DIM) ? Ab[(size_t)gm * DIM + gk + q]
                                                          : (uint16_t)0;
                }
            }
            *(bf16x8*)&Bs[row][col] =
                *(const bf16x8*)&Bt[(size_t)(n0 + row) * 512 + k0 + col];
        }
        __syncthreads();

        int ks = (lane >> 4) * 8;
        int rl = lane & 15;
        bf16x8 af[4][2], bfr[4][2];
#pragma unroll
        for (int mt = 0; mt < 4; mt++) {
            af[mt][0] = *(const bf16x8*)&As[wm * 64 + mt * 16 + rl][ks];
            af[mt][1] = *(const bf16x8*)&As[wm * 64 + mt * 16 + rl][32 + ks];
        }
#pragma unroll
        for (int nt = 0; nt < 4; nt++) {
            bfr[nt][0] = *(const bf16x8*)&Bs[wn * 64 + nt * 16 + rl][ks];
            bfr[nt][1] = *(const bf16x8*)&Bs[wn * 64 + nt * 16 + rl][32 + ks];
        }
#pragma unroll
        for (int mt = 0; mt < 4; mt++)
#pragma unroll
            for (int nt = 0; nt < 4; nt++) {
                acc[mt][nt] = __builtin_amdgcn_mfma_f32_16x16x32_bf16(
                    af[mt][0], bfr[nt][0], acc[mt][nt], 0, 0, 0);
                acc[mt][nt] = __builtin_amdgcn_mfma_f32_16x16x32_bf16(
                    af[mt][1], bfr[nt][1], acc[mt][nt], 0, 0, 0);
            }
        __syncthreads();
    }

    // epilogue: v = relu(acc + msg); C/D layout col=lane&15, row=(lane>>4)*4+q
    int cl = lane & 15;
    int rq = (lane >> 4) << 2;
#pragma unroll
    for (int mt = 0; mt < 4; mt++) {
        int rbase = m0 + wm * 64 + mt * 16 + rq;
#pragma unroll
        for (int nt = 0; nt < 4; nt++) {
            int col = n0 + wn * 64 + nt * 16 + cl;
            if (col < DIM) {
#pragma unroll
                for (int q = 0; q < 4; q++) {
                    int rr = rbase + q;
                    if (rr < M) {
                        size_t idx = (size_t)rr * DIM + col;
                        float v = acc[mt][nt][q] + msg[idx];
                        v = fmaxf(v, 0.f);
                        if (OUTBF16) houtf[idx] = f2bf(v);
                        else         outf[idx] = v;
                    }
                }
            }
        }
    }
}

// ---------------- message-sum gather (no self, no epilogue) ----------------
// Writes per-node message sums (f32) to msgsum (d_out used as scratch).
template <bool BF16H>
__global__ __launch_bounds__(256) void gather_msg_kernel(
        const void* __restrict__ h, const float* __restrict__ wexp,
        const uint2* __restrict__ elist2, const uint32_t* __restrict__ rowptr,
        float* __restrict__ msgsum) {
    int n = blockIdx.x;
    int wv = threadIdx.x >> 6, l = threadIdx.x & 63;
    const int D0 = wv * 125;
    const int j0 = l, j1 = l + 64;
    const bool has1 = (j1 < 125);
    const int b0 = j0 / 5;
    const int b1 = j1 / 5;

    __shared__ float hsb[4][2][128];

    uint32_t s = rowptr[n], e = rowptr[n + 1];
    float a0 = 0.f, a1 = 0.f;

    for (uint32_t p = s; p < e; p += 4) {
        const int k = (int)min(4u, e - p);
        uint2 rec[4];
#pragma unroll
        for (int i = 0; i < 4; i++) {
            if (i < k) rec[i] = elist2[p + i];
        }
        float v0[4], v1[4];
#pragma unroll
        for (int i = 0; i < 4; i++) {
            if (i < k) {
                uint32_t src = rec[i].x & 0xFFFFFu;
                if constexpr (BF16H) {
                    const uint16_t* row = (const uint16_t*)h + (size_t)src * DIM + D0;
                    v0[i] = bf2f(row[j0]);
                    v1[i] = has1 ? bf2f(row[j1]) : 0.f;
                } else {
                    const float* row = (const float*)h + (size_t)src * DIM + D0;
                    v0[i] = row[j0];
                    v1[i] = has1 ? row[j1] : 0.f;
                }
            }
        }
#pragma unroll
        for (int i = 0; i < 4; i++) {
            if (i < k) {
                float* hs = hsb[wv][i & 1];
                hs[j0] = v0[i];
                if (has1) hs[j1] = v1[i];
                uint32_t rl = rec[i].x >> 20;
                float inv = __uint_as_float(rec[i].y);
                const float* wbase = wexp + (size_t)rl * (5 * DIM) + D0;
                float w0[5];
#pragma unroll
                for (int q = 0; q < 5; q++) w0[q] = wbase[q * DIM + j0];
                const float* hp0 = hs + b0 * 5;
                float d0 = hp0[0] * w0[0] + hp0[1] * w0[1] + hp0[2] * w0[2]
                         + hp0[3] * w0[3] + hp0[4] * w0[4];
                a0 = fmaf(inv, d0, a0);
                if (has1) {
                    float w1[5];
#pragma unroll
                    for (int q = 0; q < 5; q++) w1[q] = wbase[q * DIM + j1];
                    const float* hp1 = hs + b1 * 5;
                    float d1 = hp1[0] * w1[0] + hp1[1] * w1[1] + hp1[2] * w1[2]
                             + hp1[3] * w1[3] + hp1[4] * w1[4];
                    a1 = fmaf(inv, d1, a1);
                }
            }
        }
    }

    long ob = (long)n * DIM + D0;
    msgsum[ob + j0] = a0;
    if (has1) msgsum[ob + j1] = a1;
}

extern "C" void kernel_launch(void* const* d_in, const int* in_sizes, int n_in,
                              void* d_out, int out_size, void* d_ws, size_t ws_size,
                              hipStream_t stream) {
    const float* x       = nullptr;
    const float* w_rel1  = nullptr;
    const float* w_rel2  = nullptr;
    const float* w_self1 = nullptr;
    const float* w_self2 = nullptr;
    const int*   eidx    = nullptr;
    for (int i = 0; i < n_in; i++) {
        int s = in_sizes[i];
        if (s == N_NODES * DIM) {
            x = (const float*)d_in[i];
        } else if (s == N_REL * 100 * 25) {
            if (!w_rel1) w_rel1 = (const float*)d_in[i];
            else         w_rel2 = (const float*)d_in[i];
        } else if (s == DIM * DIM) {
            if (!w_self1) w_self1 = (const float*)d_in[i];
            else          w_self2 = (const float*)d_in[i];
        } else if (s == N_REL * 2 * N_EDGE) {
            eidx = (const int*)d_in[i];
        }
    }
    float* out = (float*)d_out;

    char* ws = (char*)d_ws;
    uint32_t* cnt_u  = (uint32_t*)(ws + INV_OFF);
    float*    inv    = (float*)(ws + INV_OFF);
    uint32_t* deg    = (uint32_t*)(ws + DEG_OFF);
    uint32_t* rowptr = (uint32_t*)(ws + ROW_OFF);
    uint32_t* scanp  = (uint32_t*)(ws + SCANP_OFF);
    uint32_t* curs   = (uint32_t*)(ws + CURS_OFF);
    uint2*    elist2 = (uint2*)(ws + ELIST_OFF);
    uint16_t* wb1    = (uint16_t*)(ws + WB1_OFF);
    uint16_t* wb2    = (uint16_t*)(ws + WB2_OFF);
    uint16_t* h1     = (uint16_t*)(ws + H1_OFF);
    float*    wexp1  = (float*)(ws + WEXP1_OFF);
    float*    wexp2  = (float*)(ws + WEXP2_OFF);

    const int NB = (N_NODES + 1023) / 1024;

    // CSR build
    zero_kernel<<<(CNT_N + N_NODES + 255) / 256, 256, 0, stream>>>(cnt_u, CNT_N + N_NODES);
    count_kernel<<<(TOT_E + 255) / 256, 256, 0, stream>>>(eidx, cnt_u, deg);
    inv_kernel<<<(CNT_N + 255) / 256, 256, 0, stream>>>(cnt_u, inv);
    scan1_kernel<<<NB, 256, 0, stream>>>(deg, rowptr, scanp);
    scan2_kernel<<<1, 128, 0, stream>>>(scanp, rowptr, NB);
    scan3_kernel<<<NB, 256, 0, stream>>>(rowptr, scanp, curs);
    scatter_kernel<<<(TOT_E + 255) / 256, 256, 0, stream>>>(eidx, inv, curs, elist2);

    // weight prep
    conv_w_kernel<<<512 * 512 / 256, 256, 0, stream>>>(w_self1, wb1);
    conv_w_kernel<<<512 * 512 / 256, 256, 0, stream>>>(w_self2, wb2);
    conv_wexp_kernel<<<(N_REL * 5 * DIM + 255) / 256, 256, 0, stream>>>(w_rel1, wexp1);
    conv_wexp_kernel<<<(N_REL * 5 * DIM + 255) / 256, 256, 0, stream>>>(w_rel2, wexp2);

    dim3 ggrid((N_NODES + 127) / 128, 4);

    // layer 1: msgsum1(d_out) = msgs(x_f32); h1 = relu(x@W1 + msgsum1)  [bf16]
    gather_msg_kernel<false><<<N_NODES, 256, 0, stream>>>(
        x, wexp1, elist2, rowptr, out);
    gemm_fused_kernel<true, true><<<ggrid, 256, 0, stream>>>(
        x, wb1, out, nullptr, h1, N_NODES);

    // layer 2: msgsum2(d_out) = msgs(h1); out = relu(h1@W2 + msgsum2)  [f32]
    gather_msg_kernel<true><<<N_NODES, 256, 0, stream>>>(
        h1, wexp2, elist2, rowptr, out);
    gemm_fused_kernel<false, false><<<ggrid, 256, 0, stream>>>(
        h1, wb2, out, out, nullptr, N_NODES);
}

// Round 20
// 1283.116 us; speedup vs baseline: 1.2121x; 1.2121x over previous
//
#include <hip/hip_runtime.h>
#include <hip/hip_bf16.h>
#include <stdint.h>

#define N_NODES 100000
#define N_REL   16
#define N_EDGE  50000
#define DIM     500
#define TOT_E   (N_REL * N_EDGE)      // 800,000
#define CNT_N   (N_REL * N_NODES)     // 1,600,000

// ws layout (8/16B-aligned):
#define INV_OFF    0ull
#define DEG_OFF    6400000ull
#define ROW_OFF    6800000ull
#define SCANP_OFF  7201000ull
#define CURS_OFF   7210000ull
#define ELIST_OFF  7610000ull     // 800k uint2
#define WB1_OFF    14020000ull
#define WB2_OFF    14550000ull
#define H1_OFF     15080000ull    // 50M bf16 h1 -> ends 115,080,000
#define WEXP1_OFF  115080000ull   // 16*5*500 f32 = 160,000 B
#define WEXP2_OFF  115240000ull   // -> end 115,400,000

typedef __attribute__((ext_vector_type(8))) short bf16x8;
typedef __attribute__((ext_vector_type(4))) float f32x4;

// ---------------- threefry2x32, partitionable-mode mask (R8-verified) ----------------
__device__ __forceinline__ uint32_t rotl32(uint32_t x, int d) {
    return (x << d) | (x >> (32 - d));
}
__device__ __forceinline__ bool edge_keep(uint32_t j) {
    uint32_t x0 = 0u, x1 = j;
    const uint32_t ks0 = 0u, ks1 = 42u, ks2 = 0u ^ 42u ^ 0x1BD11BDAu;
    const int RA[4] = {13, 15, 26, 6};
    const int RB[4] = {17, 29, 16, 24};
    x0 += ks0; x1 += ks1;
#pragma unroll
    for (int i = 0; i < 4; i++) { x0 += x1; x1 = rotl32(x1, RA[i]); x1 ^= x0; }
    x0 += ks1; x1 += ks2 + 1u;
#pragma unroll
    for (int i = 0; i < 4; i++) { x0 += x1; x1 = rotl32(x1, RB[i]); x1 ^= x0; }
    x0 += ks2; x1 += ks0 + 2u;
#pragma unroll
    for (int i = 0; i < 4; i++) { x0 += x1; x1 = rotl32(x1, RA[i]); x1 ^= x0; }
    x0 += ks0; x1 += ks1 + 3u;
#pragma unroll
    for (int i = 0; i < 4; i++) { x0 += x1; x1 = rotl32(x1, RB[i]); x1 ^= x0; }
    x0 += ks1; x1 += ks2 + 4u;
#pragma unroll
    for (int i = 0; i < 4; i++) { x0 += x1; x1 = rotl32(x1, RA[i]); x1 ^= x0; }
    x0 += ks2; x1 += ks0 + 5u;
    return ((x0 ^ x1) >> 31) == 0u;
}

__device__ __forceinline__ uint16_t f2bf(float f) {
    uint32_t u = __float_as_uint(f);
    u += 0x7FFFu + ((u >> 16) & 1u);
    return (uint16_t)(u >> 16);
}
__device__ __forceinline__ float bf2f(uint16_t v) {
    return __uint_as_float((uint32_t)v << 16);
}

// ---------------- CSR build ----------------
__global__ __launch_bounds__(256) void zero_kernel(uint32_t* __restrict__ p, int n) {
    int t = blockIdx.x * blockDim.x + threadIdx.x;
    if (t < n) p[t] = 0u;
}

__global__ __launch_bounds__(256) void count_kernel(
        const int* __restrict__ eidx, uint32_t* __restrict__ cnt,
        uint32_t* __restrict__ deg) {
    int tid = blockIdx.x * blockDim.x + threadIdx.x;
    if (tid >= TOT_E) return;
    if (edge_keep((uint32_t)tid)) {
        int r = tid / N_EDGE;
        int e = tid - r * N_EDGE;
        int dst = eidx[(r * 2 + 1) * N_EDGE + e];
        atomicAdd(&cnt[r * N_NODES + dst], 1u);
        atomicAdd(&deg[dst], 1u);
    }
}

__global__ __launch_bounds__(256) void inv_kernel(uint32_t* __restrict__ cnt_u,
                                                  float* __restrict__ inv) {
    int t = blockIdx.x * blockDim.x + threadIdx.x;
    if (t < CNT_N) {
        float c = (float)cnt_u[t];
        inv[t] = 1.0f / fmaxf(c, 1.0f);
    }
}

__global__ __launch_bounds__(256) void scan1_kernel(
        const uint32_t* __restrict__ deg, uint32_t* __restrict__ rowptr,
        uint32_t* __restrict__ scanp) {
    __shared__ uint32_t sh[256];
    int b = blockIdx.x, t = threadIdx.x;
    int base = b * 1024 + t * 4;
    uint32_t x[4];
#pragma unroll
    for (int i = 0; i < 4; i++) x[i] = (base + i < N_NODES) ? deg[base + i] : 0u;
    uint32_t s = x[0] + x[1] + x[2] + x[3];
    sh[t] = s; __syncthreads();
    for (int off = 1; off < 256; off <<= 1) {
        uint32_t v = (t >= off) ? sh[t - off] : 0u;
        __syncthreads();
        sh[t] += v;
        __syncthreads();
    }
    uint32_t run = sh[t] - s;
    if (t == 255) scanp[b] = sh[255];
#pragma unroll
    for (int i = 0; i < 4; i++) {
        if (base + i < N_NODES) rowptr[base + i] = run;
        run += x[i];
    }
}

__global__ __launch_bounds__(128) void scan2_kernel(
        uint32_t* __restrict__ scanp, uint32_t* __restrict__ rowptr, int nb) {
    __shared__ uint32_t sh[128];
    int t = threadIdx.x;
    uint32_t v = (t < nb) ? scanp[t] : 0u;
    sh[t] = v; __syncthreads();
    for (int off = 1; off < 128; off <<= 1) {
        uint32_t u = (t >= off) ? sh[t - off] : 0u;
        __syncthreads();
        sh[t] += u;
        __syncthreads();
    }
    if (t < nb) scanp[t] = sh[t] - v;
    if (t == 127) rowptr[N_NODES] = sh[127];
}

__global__ __launch_bounds__(256) void scan3_kernel(
        uint32_t* __restrict__ rowptr, const uint32_t* __restrict__ scanp,
        uint32_t* __restrict__ curs) {
    int b = blockIdx.x, t = threadIdx.x;
    int base = b * 1024 + t * 4;
    uint32_t off = scanp[b];
#pragma unroll
    for (int i = 0; i < 4; i++) {
        int idx = base + i;
        if (idx < N_NODES) {
            uint32_t v = rowptr[idx] + off;
            rowptr[idx] = v;
            curs[idx] = v;
        }
    }
}

__global__ __launch_bounds__(256) void scatter_kernel(
        const int* __restrict__ eidx, const float* __restrict__ inv,
        uint32_t* __restrict__ curs, uint2* __restrict__ elist2) {
    int tid = blockIdx.x * blockDim.x + threadIdx.x;
    if (tid >= TOT_E) return;
    if (edge_keep((uint32_t)tid)) {
        int r = tid / N_EDGE;
        int e = tid - r * N_EDGE;
        int src = eidx[(r * 2 + 0) * N_EDGE + e];
        int dst = eidx[(r * 2 + 1) * N_EDGE + e];
        uint32_t pos = atomicAdd(&curs[dst], 1u);
        uint2 rec;
        rec.x = (uint32_t)src | ((uint32_t)r << 20);
        rec.y = __float_as_uint(inv[r * N_NODES + dst]);
        elist2[pos] = rec;
    }
}

// ---------------- weight conversions ----------------
__global__ __launch_bounds__(256) void conv_w_kernel(
        const float* __restrict__ W, uint16_t* __restrict__ Bt) {
    int idx = blockIdx.x * 256 + threadIdx.x;
    int n = idx >> 9, k = idx & 511;
    float v = (n < DIM && k < DIM) ? W[k * DIM + n] : 0.f;
    Bt[idx] = f2bf(v);
}

// wexp[r][i][j] = w_rel[r][j/5][i][j%5]  (16 x 5 x 500 f32): lane-j coalesced
__global__ __launch_bounds__(256) void conv_wexp_kernel(
        const float* __restrict__ W, float* __restrict__ wexp) {
    int idx = blockIdx.x * 256 + threadIdx.x;
    if (idx >= N_REL * 5 * DIM) return;
    int r = idx / (5 * DIM);
    int rem = idx - r * 5 * DIM;
    int i = rem / DIM;
    int j = rem - i * DIM;
    wexp[idx] = W[r * 2500 + (j / 5) * 25 + i * 5 + (j % 5)];
}

// ---------------- MFMA bf16 GEMM 128x128 + fused epilogue (batched) ----------------
// 1D grid with m-group XCD swizzle: the 4 column-blocks of one A-panel are
// temporally adjacent on the SAME XCD -> A re-reads hit that XCD's L2.
// Epilogue: per-mt BATCHED msg loads (no interleaved stores -> pipelined
// despite msg/outf aliasing in layer 2).
template <bool AF32, bool OUTBF16>
__global__ __launch_bounds__(256) void gemm_fused_kernel(
        const void* __restrict__ A, const uint16_t* __restrict__ Bt,
        const float* msg, float* outf, uint16_t* houtf, int M) {
    int bid = blockIdx.x;
    int xcd = bid & 7;
    int slot = bid >> 3;
    int nblk = slot & 3;
    int mloc = slot >> 2;
    int mblk = mloc * 8 + xcd;
    if (mblk >= (N_NODES + 127) / 128) return;
    int m0 = mblk * 128;
    int n0 = nblk * 128;

    __shared__ uint16_t As[128][72];
    __shared__ uint16_t Bs[128][72];
    int t = threadIdx.x;
    int wave = t >> 6, lane = t & 63;
    int wm = wave >> 1, wn = wave & 1;
    f32x4 acc[4][4] = {};

    for (int k0 = 0; k0 < 512; k0 += 64) {
#pragma unroll
        for (int i = 0; i < 4; i++) {
            int c = t * 4 + i;             // 0..1023
            int row = c >> 3;              // 0..127
            int col = (c & 7) * 8;         // 0..56
            int gm = m0 + row, gk = k0 + col;
            uint16_t* dst = &As[row][col];
            if constexpr (AF32) {
                const float* Af = (const float*)A;
                if (gm < M && gk + 7 < DIM) {
                    float4 p0 = *(const float4*)&Af[(size_t)gm * DIM + gk];
                    float4 p1 = *(const float4*)&Af[(size_t)gm * DIM + gk + 4];
                    dst[0] = f2bf(p0.x); dst[1] = f2bf(p0.y);
                    dst[2] = f2bf(p0.z); dst[3] = f2bf(p0.w);
                    dst[4] = f2bf(p1.x); dst[5] = f2bf(p1.y);
                    dst[6] = f2bf(p1.z); dst[7] = f2bf(p1.w);
                } else {
#pragma unroll
                    for (int q = 0; q < 8; q++)
                        dst[q] = (gm < M && gk + q < DIM)
                                     ? f2bf(Af[(size_t)gm * DIM + gk + q]) : (uint16_t)0;
                }
            } else {
                const uint16_t* Ab = (const uint16_t*)A;
                if (gm < M && gk + 7 < DIM) {
                    *(bf16x8*)dst = *(const bf16x8*)&Ab[(size_t)gm * DIM + gk];
                } else {
#pragma unroll
                    for (int q = 0; q < 8; q++)
                        dst[q] = (gm < M && gk + q < DIM) ? Ab[(size_t)gm * DIM + gk + q]
                                                          : (uint16_t)0;
                }
            }
            *(bf16x8*)&Bs[row][col] =
                *(const bf16x8*)&Bt[(size_t)(n0 + row) * 512 + k0 + col];
        }
        __syncthreads();

        int ks = (lane >> 4) * 8;
        int rl = lane & 15;
        bf16x8 af[4][2], bfr[4][2];
#pragma unroll
        for (int mt = 0; mt < 4; mt++) {
            af[mt][0] = *(const bf16x8*)&As[wm * 64 + mt * 16 + rl][ks];
            af[mt][1] = *(const bf16x8*)&As[wm * 64 + mt * 16 + rl][32 + ks];
        }
#pragma unroll
        for (int nt = 0; nt < 4; nt++) {
            bfr[nt][0] = *(const bf16x8*)&Bs[wn * 64 + nt * 16 + rl][ks];
            bfr[nt][1] = *(const bf16x8*)&Bs[wn * 64 + nt * 16 + rl][32 + ks];
        }
#pragma unroll
        for (int mt = 0; mt < 4; mt++)
#pragma unroll
            for (int nt = 0; nt < 4; nt++) {
                acc[mt][nt] = __builtin_amdgcn_mfma_f32_16x16x32_bf16(
                    af[mt][0], bfr[nt][0], acc[mt][nt], 0, 0, 0);
                acc[mt][nt] = __builtin_amdgcn_mfma_f32_16x16x32_bf16(
                    af[mt][1], bfr[nt][1], acc[mt][nt], 0, 0, 0);
            }
        __syncthreads();
    }

    // epilogue: v = relu(acc + msg). C/D layout col=lane&15, row=(lane>>4)*4+q.
    // Per-mt: batch all 16 msg loads FIRST (pipelined), then compute+store.
    int cl = lane & 15;
    int rq = (lane >> 4) << 2;
#pragma unroll
    for (int mt = 0; mt < 4; mt++) {
        int rbase = m0 + wm * 64 + mt * 16 + rq;
        float msgv[4][4];
#pragma unroll
        for (int nt = 0; nt < 4; nt++) {
            int col = n0 + wn * 64 + nt * 16 + cl;
#pragma unroll
            for (int q = 0; q < 4; q++) {
                int rr = rbase + q;
                msgv[nt][q] = (col < DIM && rr < M) ? msg[(size_t)rr * DIM + col] : 0.f;
            }
        }
#pragma unroll
        for (int nt = 0; nt < 4; nt++) {
            int col = n0 + wn * 64 + nt * 16 + cl;
            if (col < DIM) {
#pragma unroll
                for (int q = 0; q < 4; q++) {
                    int rr = rbase + q;
                    if (rr < M) {
                        size_t idx = (size_t)rr * DIM + col;
                        float v = fmaxf(acc[mt][nt][q] + msgv[nt][q], 0.f);
                        if (OUTBF16) houtf[idx] = f2bf(v);
                        else         outf[idx] = v;
                    }
                }
            }
        }
    }
}

// ---------------- message-sum gather (no self, no epilogue) ----------------
template <bool BF16H>
__global__ __launch_bounds__(256) void gather_msg_kernel(
        const void* __restrict__ h, const float* __restrict__ wexp,
        const uint2* __restrict__ elist2, const uint32_t* __restrict__ rowptr,
        float* __restrict__ msgsum) {
    int n = blockIdx.x;
    int wv = threadIdx.x >> 6, l = threadIdx.x & 63;
    const int D0 = wv * 125;
    const int j0 = l, j1 = l + 64;
    const bool has1 = (j1 < 125);
    const int b0 = j0 / 5;
    const int b1 = j1 / 5;

    __shared__ float hsb[4][2][128];

    uint32_t s = rowptr[n], e = rowptr[n + 1];
    float a0 = 0.f, a1 = 0.f;

    for (uint32_t p = s; p < e; p += 4) {
        const int k = (int)min(4u, e - p);
        uint2 rec[4];
#pragma unroll
        for (int i = 0; i < 4; i++) {
            if (i < k) rec[i] = elist2[p + i];
        }
        float v0[4], v1[4];
#pragma unroll
        for (int i = 0; i < 4; i++) {
            if (i < k) {
                uint32_t src = rec[i].x & 0xFFFFFu;
                if constexpr (BF16H) {
                    const uint16_t* row = (const uint16_t*)h + (size_t)src * DIM + D0;
                    v0[i] = bf2f(row[j0]);
                    v1[i] = has1 ? bf2f(row[j1]) : 0.f;
                } else {
                    const float* row = (const float*)h + (size_t)src * DIM + D0;
                    v0[i] = row[j0];
                    v1[i] = has1 ? row[j1] : 0.f;
                }
            }
        }
#pragma unroll
        for (int i = 0; i < 4; i++) {
            if (i < k) {
                float* hs = hsb[wv][i & 1];
                hs[j0] = v0[i];
                if (has1) hs[j1] = v1[i];
                uint32_t rl = rec[i].x >> 20;
                float inv = __uint_as_float(rec[i].y);
                const float* wbase = wexp + (size_t)rl * (5 * DIM) + D0;
                float w0[5];
#pragma unroll
                for (int q = 0; q < 5; q++) w0[q] = wbase[q * DIM + j0];
                const float* hp0 = hs + b0 * 5;
                float d0 = hp0[0] * w0[0] + hp0[1] * w0[1] + hp0[2] * w0[2]
                         + hp0[3] * w0[3] + hp0[4] * w0[4];
                a0 = fmaf(inv, d0, a0);
                if (has1) {
                    float w1[5];
#pragma unroll
                    for (int q = 0; q < 5; q++) w1[q] = wbase[q * DIM + j1];
                    const float* hp1 = hs + b1 * 5;
                    float d1 = hp1[0] * w1[0] + hp1[1] * w1[1] + hp1[2] * w1[2]
                             + hp1[3] * w1[3] + hp1[4] * w1[4];
                    a1 = fmaf(inv, d1, a1);
                }
            }
        }
    }

    long ob = (long)n * DIM + D0;
    msgsum[ob + j0] = a0;
    if (has1) msgsum[ob + j1] = a1;
}

extern "C" void kernel_launch(void* const* d_in, const int* in_sizes, int n_in,
                              void* d_out, int out_size, void* d_ws, size_t ws_size,
                              hipStream_t stream) {
    const float* x       = nullptr;
    const float* w_rel1  = nullptr;
    const float* w_rel2  = nullptr;
    const float* w_self1 = nullptr;
    const float* w_self2 = nullptr;
    const int*   eidx    = nullptr;
    for (int i = 0; i < n_in; i++) {
        int s = in_sizes[i];
        if (s == N_NODES * DIM) {
            x = (const float*)d_in[i];
        } else if (s == N_REL * 100 * 25) {
            if (!w_rel1) w_rel1 = (const float*)d_in[i];
            else         w_rel2 = (const float*)d_in[i];
        } else if (s == DIM * DIM) {
            if (!w_self1) w_self1 = (const float*)d_in[i];
            else          w_self2 = (const float*)d_in[i];
        } else if (s == N_REL * 2 * N_EDGE) {
            eidx = (const int*)d_in[i];
        }
    }
    float* out = (float*)d_out;

    char* ws = (char*)d_ws;
    uint32_t* cnt_u  = (uint32_t*)(ws + INV_OFF);
    float*    inv    = (float*)(ws + INV_OFF);
    uint32_t* deg    = (uint32_t*)(ws + DEG_OFF);
    uint32_t* rowptr = (uint32_t*)(ws + ROW_OFF);
    uint32_t* scanp  = (uint32_t*)(ws + SCANP_OFF);
    uint32_t* curs   = (uint32_t*)(ws + CURS_OFF);
    uint2*    elist2 = (uint2*)(ws + ELIST_OFF);
    uint16_t* wb1    = (uint16_t*)(ws + WB1_OFF);
    uint16_t* wb2    = (uint16_t*)(ws + WB2_OFF);
    uint16_t* h1     = (uint16_t*)(ws + H1_OFF);
    float*    wexp1  = (float*)(ws + WEXP1_OFF);
    float*    wexp2  = (float*)(ws + WEXP2_OFF);

    const int NB = (N_NODES + 1023) / 1024;

    // CSR build
    zero_kernel<<<(CNT_N + N_NODES + 255) / 256, 256, 0, stream>>>(cnt_u, CNT_N + N_NODES);
    count_kernel<<<(TOT_E + 255) / 256, 256, 0, stream>>>(eidx, cnt_u, deg);
    inv_kernel<<<(CNT_N + 255) / 256, 256, 0, stream>>>(cnt_u, inv);
    scan1_kernel<<<NB, 256, 0, stream>>>(deg, rowptr, scanp);
    scan2_kernel<<<1, 128, 0, stream>>>(scanp, rowptr, NB);
    scan3_kernel<<<NB, 256, 0, stream>>>(rowptr, scanp, curs);
    scatter_kernel<<<(TOT_E + 255) / 256, 256, 0, stream>>>(eidx, inv, curs, elist2);

    // weight prep
    conv_w_kernel<<<512 * 512 / 256, 256, 0, stream>>>(w_self1, wb1);
    conv_w_kernel<<<512 * 512 / 256, 256, 0, stream>>>(w_self2, wb2);
    conv_wexp_kernel<<<(N_REL * 5 * DIM + 255) / 256, 256, 0, stream>>>(w_rel1, wexp1);
    conv_wexp_kernel<<<(N_REL * 5 * DIM + 255) / 256, 256, 0, stream>>>(w_rel2, wexp2);

    // swizzled 1D grid: ceil(782/8)=98 m-locs x 8 xcd x 4 nblk = 3136 blocks
    const int GB = 98 * 8 * 4;

    // layer 1: msgsum1(d_out) = msgs(x_f32); h1 = relu(x@W1 + msgsum1)  [bf16]
    gather_msg_kernel<false><<<N_NODES, 256, 0, stream>>>(
        x, wexp1, elist2, rowptr, out);
    gemm_fused_kernel<true, true><<<GB, 256, 0, stream>>>(
        x, wb1, out, nullptr, h1, N_NODES);

    // layer 2: msgsum2(d_out) = msgs(h1); out = relu(h1@W2 + msgsum2)  [f32]
    gather_msg_kernel<true><<<N_NODES, 256, 0, stream>>>(
        h1, wexp2, elist2, rowptr, out);
    gemm_fused_kernel<false, false><<<GB, 256, 0, stream>>>(
        h1, wb2, out, out, nullptr, N_NODES);
}

// Round 21
// 1280.964 us; speedup vs baseline: 1.2141x; 1.0017x over previous
//
#include <hip/hip_runtime.h>
#include <hip/hip_bf16.h>
#include <stdint.h>

#define N_NODES 100000
#define N_REL   16
#define N_EDGE  50000
#define DIM     500
#define TOT_E   (N_REL * N_EDGE)      // 800,000
#define CNT_N   (N_REL * N_NODES)     // 1,600,000

// ws layout (8/16B-aligned):
#define INV_OFF    0ull
#define DEG_OFF    6400000ull
#define ROW_OFF    6800000ull
#define SCANP_OFF  7201000ull
#define CURS_OFF   7210000ull
#define ELIST_OFF  7610000ull     // 800k uint2
#define WB1_OFF    14020000ull
#define WB2_OFF    14550000ull
#define H1_OFF     15080000ull    // 50M bf16 h1 -> ends 115,080,000
#define WEXP1_OFF  115080000ull   // 16*5*500 f32 = 160,000 B
#define WEXP2_OFF  115240000ull   // -> end 115,400,000

typedef __attribute__((ext_vector_type(8))) short bf16x8;
typedef __attribute__((ext_vector_type(4))) float f32x4;

// ---------------- threefry2x32, partitionable-mode mask (R8-verified) ----------------
__device__ __forceinline__ uint32_t rotl32(uint32_t x, int d) {
    return (x << d) | (x >> (32 - d));
}
__device__ __forceinline__ bool edge_keep(uint32_t j) {
    uint32_t x0 = 0u, x1 = j;
    const uint32_t ks0 = 0u, ks1 = 42u, ks2 = 0u ^ 42u ^ 0x1BD11BDAu;
    const int RA[4] = {13, 15, 26, 6};
    const int RB[4] = {17, 29, 16, 24};
    x0 += ks0; x1 += ks1;
#pragma unroll
    for (int i = 0; i < 4; i++) { x0 += x1; x1 = rotl32(x1, RA[i]); x1 ^= x0; }
    x0 += ks1; x1 += ks2 + 1u;
#pragma unroll
    for (int i = 0; i < 4; i++) { x0 += x1; x1 = rotl32(x1, RB[i]); x1 ^= x0; }
    x0 += ks2; x1 += ks0 + 2u;
#pragma unroll
    for (int i = 0; i < 4; i++) { x0 += x1; x1 = rotl32(x1, RA[i]); x1 ^= x0; }
    x0 += ks0; x1 += ks1 + 3u;
#pragma unroll
    for (int i = 0; i < 4; i++) { x0 += x1; x1 = rotl32(x1, RB[i]); x1 ^= x0; }
    x0 += ks1; x1 += ks2 + 4u;
#pragma unroll
    for (int i = 0; i < 4; i++) { x0 += x1; x1 = rotl32(x1, RA[i]); x1 ^= x0; }
    x0 += ks2; x1 += ks0 + 5u;
    return ((x0 ^ x1) >> 31) == 0u;
}

__device__ __forceinline__ uint16_t f2bf(float f) {
    uint32_t u = __float_as_uint(f);
    u += 0x7FFFu + ((u >> 16) & 1u);
    return (uint16_t)(u >> 16);
}
__device__ __forceinline__ float bf2f(uint16_t v) {
    return __uint_as_float((uint32_t)v << 16);
}

// ---------------- CSR build ----------------
__global__ __launch_bounds__(256) void zero_kernel(uint32_t* __restrict__ p, int n) {
    int t = blockIdx.x * blockDim.x + threadIdx.x;
    if (t < n) p[t] = 0u;
}

__global__ __launch_bounds__(256) void count_kernel(
        const int* __restrict__ eidx, uint32_t* __restrict__ cnt,
        uint32_t* __restrict__ deg) {
    int tid = blockIdx.x * blockDim.x + threadIdx.x;
    if (tid >= TOT_E) return;
    if (edge_keep((uint32_t)tid)) {
        int r = tid / N_EDGE;
        int e = tid - r * N_EDGE;
        int dst = eidx[(r * 2 + 1) * N_EDGE + e];
        atomicAdd(&cnt[r * N_NODES + dst], 1u);
        atomicAdd(&deg[dst], 1u);
    }
}

__global__ __launch_bounds__(256) void inv_kernel(uint32_t* __restrict__ cnt_u,
                                                  float* __restrict__ inv) {
    int t = blockIdx.x * blockDim.x + threadIdx.x;
    if (t < CNT_N) {
        float c = (float)cnt_u[t];
        inv[t] = 1.0f / fmaxf(c, 1.0f);
    }
}

__global__ __launch_bounds__(256) void scan1_kernel(
        const uint32_t* __restrict__ deg, uint32_t* __restrict__ rowptr,
        uint32_t* __restrict__ scanp) {
    __shared__ uint32_t sh[256];
    int b = blockIdx.x, t = threadIdx.x;
    int base = b * 1024 + t * 4;
    uint32_t x[4];
#pragma unroll
    for (int i = 0; i < 4; i++) x[i] = (base + i < N_NODES) ? deg[base + i] : 0u;
    uint32_t s = x[0] + x[1] + x[2] + x[3];
    sh[t] = s; __syncthreads();
    for (int off = 1; off < 256; off <<= 1) {
        uint32_t v = (t >= off) ? sh[t - off] : 0u;
        __syncthreads();
        sh[t] += v;
        __syncthreads();
    }
    uint32_t run = sh[t] - s;
    if (t == 255) scanp[b] = sh[255];
#pragma unroll
    for (int i = 0; i < 4; i++) {
        if (base + i < N_NODES) rowptr[base + i] = run;
        run += x[i];
    }
}

__global__ __launch_bounds__(128) void scan2_kernel(
        uint32_t* __restrict__ scanp, uint32_t* __restrict__ rowptr, int nb) {
    __shared__ uint32_t sh[128];
    int t = threadIdx.x;
    uint32_t v = (t < nb) ? scanp[t] : 0u;
    sh[t] = v; __syncthreads();
    for (int off = 1; off < 128; off <<= 1) {
        uint32_t u = (t >= off) ? sh[t - off] : 0u;
        __syncthreads();
        sh[t] += u;
        __syncthreads();
    }
    if (t < nb) scanp[t] = sh[t] - v;
    if (t == 127) rowptr[N_NODES] = sh[127];
}

__global__ __launch_bounds__(256) void scan3_kernel(
        uint32_t* __restrict__ rowptr, const uint32_t* __restrict__ scanp,
        uint32_t* __restrict__ curs) {
    int b = blockIdx.x, t = threadIdx.x;
    int base = b * 1024 + t * 4;
    uint32_t off = scanp[b];
#pragma unroll
    for (int i = 0; i < 4; i++) {
        int idx = base + i;
        if (idx < N_NODES) {
            uint32_t v = rowptr[idx] + off;
            rowptr[idx] = v;
            curs[idx] = v;
        }
    }
}

__global__ __launch_bounds__(256) void scatter_kernel(
        const int* __restrict__ eidx, const float* __restrict__ inv,
        uint32_t* __restrict__ curs, uint2* __restrict__ elist2) {
    int tid = blockIdx.x * blockDim.x + threadIdx.x;
    if (tid >= TOT_E) return;
    if (edge_keep((uint32_t)tid)) {
        int r = tid / N_EDGE;
        int e = tid - r * N_EDGE;
        int src = eidx[(r * 2 + 0) * N_EDGE + e];
        int dst = eidx[(r * 2 + 1) * N_EDGE + e];
        uint32_t pos = atomicAdd(&curs[dst], 1u);
        uint2 rec;
        rec.x = (uint32_t)src | ((uint32_t)r << 20);
        rec.y = __float_as_uint(inv[r * N_NODES + dst]);
        elist2[pos] = rec;
    }
}

// ---------------- weight conversions ----------------
__global__ __launch_bounds__(256) void conv_w_kernel(
        const float* __restrict__ W, uint16_t* __restrict__ Bt) {
    int idx = blockIdx.x * 256 + threadIdx.x;
    int n = idx >> 9, k = idx & 511;
    float v = (n < DIM && k < DIM) ? W[k * DIM + n] : 0.f;
    Bt[idx] = f2bf(v);
}

// wexp[r][i][j] = w_rel[r][j/5][i][j%5]  (16 x 5 x 500 f32): lane-j coalesced
__global__ __launch_bounds__(256) void conv_wexp_kernel(
        const float* __restrict__ W, float* __restrict__ wexp) {
    int idx = blockIdx.x * 256 + threadIdx.x;
    if (idx >= N_REL * 5 * DIM) return;
    int r = idx / (5 * DIM);
    int rem = idx - r * 5 * DIM;
    int i = rem / DIM;
    int j = rem - i * DIM;
    wexp[idx] = W[r * 2500 + (j / 5) * 25 + i * 5 + (j % 5)];
}

// ---------------- MFMA bf16 GEMM 128x128 + LDS-STAGED fused epilogue ----------------
// m-group XCD swizzle (A-panel L2 locality). Epilogue per 64-row half:
// coalesced msg->LDS, in-LDS acc add (scatter stays LDS-side), coalesced
// relu+store. Alias-safe: block-private tile, barrier-ordered load->store.
template <bool AF32, bool OUTBF16>
__global__ __launch_bounds__(256) void gemm_fused_kernel(
        const void* __restrict__ A, const uint16_t* __restrict__ Bt,
        const float* msg, float* outf, uint16_t* houtf, int M) {
    int bid = blockIdx.x;
    int xcd = bid & 7;
    int slot = bid >> 3;
    int nblk = slot & 3;
    int mloc = slot >> 2;
    int mblk = mloc * 8 + xcd;
    if (mblk >= (N_NODES + 127) / 128) return;
    int m0 = mblk * 128;
    int n0 = nblk * 128;

    __shared__ __align__(16) char smem[36864];
    uint16_t (*As)[72] = (uint16_t(*)[72])smem;
    uint16_t (*Bs)[72] = (uint16_t(*)[72])(smem + 128 * 72 * 2);
    float* ctile = (float*)smem;               // 64x128 f32 = 32768 B (epilogue)

    int t = threadIdx.x;
    int wave = t >> 6, lane = t & 63;
    int wm = wave >> 1, wn = wave & 1;
    f32x4 acc[4][4] = {};

    for (int k0 = 0; k0 < 512; k0 += 64) {
#pragma unroll
        for (int i = 0; i < 4; i++) {
            int c = t * 4 + i;             // 0..1023
            int row = c >> 3;              // 0..127
            int col = (c & 7) * 8;         // 0..56
            int gm = m0 + row, gk = k0 + col;
            uint16_t* dst = &As[row][col];
            if constexpr (AF32) {
                const float* Af = (const float*)A;
                if (gm < M && gk + 7 < DIM) {
                    float4 p0 = *(const float4*)&Af[(size_t)gm * DIM + gk];
                    float4 p1 = *(const float4*)&Af[(size_t)gm * DIM + gk + 4];
                    dst[0] = f2bf(p0.x); dst[1] = f2bf(p0.y);
                    dst[2] = f2bf(p0.z); dst[3] = f2bf(p0.w);
                    dst[4] = f2bf(p1.x); dst[5] = f2bf(p1.y);
                    dst[6] = f2bf(p1.z); dst[7] = f2bf(p1.w);
                } else {
#pragma unroll
                    for (int q = 0; q < 8; q++)
                        dst[q] = (gm < M && gk + q < DIM)
                                     ? f2bf(Af[(size_t)gm * DIM + gk + q]) : (uint16_t)0;
                }
            } else {
                const uint16_t* Ab = (const uint16_t*)A;
                if (gm < M && gk + 7 < DIM) {
                    *(bf16x8*)dst = *(const bf16x8*)&Ab[(size_t)gm * DIM + gk];
                } else {
#pragma unroll
                    for (int q = 0; q < 8; q++)
                        dst[q] = (gm < M && gk + q < DIM) ? Ab[(size_t)gm * DIM + gk + q]
                                                          : (uint16_t)0;
                }
            }
            *(bf16x8*)&Bs[row][col] =
                *(const bf16x8*)&Bt[(size_t)(n0 + row) * 512 + k0 + col];
        }
        __syncthreads();

        int ks = (lane >> 4) * 8;
        int rl = lane & 15;
        bf16x8 af[4][2], bfr[4][2];
#pragma unroll
        for (int mt = 0; mt < 4; mt++) {
            af[mt][0] = *(const bf16x8*)&As[wm * 64 + mt * 16 + rl][ks];
            af[mt][1] = *(const bf16x8*)&As[wm * 64 + mt * 16 + rl][32 + ks];
        }
#pragma unroll
        for (int nt = 0; nt < 4; nt++) {
            bfr[nt][0] = *(const bf16x8*)&Bs[wn * 64 + nt * 16 + rl][ks];
            bfr[nt][1] = *(const bf16x8*)&Bs[wn * 64 + nt * 16 + rl][32 + ks];
        }
#pragma unroll
        for (int mt = 0; mt < 4; mt++)
#pragma unroll
            for (int nt = 0; nt < 4; nt++) {
                acc[mt][nt] = __builtin_amdgcn_mfma_f32_16x16x32_bf16(
                    af[mt][0], bfr[nt][0], acc[mt][nt], 0, 0, 0);
                acc[mt][nt] = __builtin_amdgcn_mfma_f32_16x16x32_bf16(
                    af[mt][1], bfr[nt][1], acc[mt][nt], 0, 0, 0);
            }
        __syncthreads();
    }

    // ---- LDS-staged epilogue: two 64-row halves ----
    int cl = lane & 15;
    int rq = (lane >> 4) << 2;
#pragma unroll
    for (int h = 0; h < 2; h++) {
        // 1) coalesced load of msg tile into LDS (zeros outside bounds)
#pragma unroll
        for (int k = 0; k < 8; k++) {
            int f = t + k * 256;           // float4 index, 2048 total
            int row = f >> 5;              // 0..63
            int c4 = (f & 31) * 4;         // 0..124
            int gr = m0 + h * 64 + row;
            int gc = n0 + c4;
            float4 v = make_float4(0.f, 0.f, 0.f, 0.f);
            if (gr < M) {
                if (gc + 3 < DIM) {
                    v = *(const float4*)&msg[(size_t)gr * DIM + gc];
                } else {
                    float* vp = (float*)&v;
#pragma unroll
                    for (int q = 0; q < 4; q++)
                        if (gc + q < DIM) vp[q] = msg[(size_t)gr * DIM + gc + q];
                }
            }
            *(float4*)&ctile[row * 128 + c4] = v;
        }
        __syncthreads();
        // 2) waves owning this half add their accumulators (LDS-side scatter)
        if (wm == h) {
#pragma unroll
            for (int mt = 0; mt < 4; mt++) {
#pragma unroll
                for (int nt = 0; nt < 4; nt++) {
                    int lc = wn * 64 + nt * 16 + cl;
#pragma unroll
                    for (int q = 0; q < 4; q++) {
                        int lr = mt * 16 + rq + q;
                        ctile[lr * 128 + lc] += acc[mt][nt][q];
                    }
                }
            }
        }
        __syncthreads();
        // 3) coalesced relu + store
#pragma unroll
        for (int k = 0; k < 8; k++) {
            int f = t + k * 256;
            int row = f >> 5;
            int c4 = (f & 31) * 4;
            int gr = m0 + h * 64 + row;
            int gc = n0 + c4;
            if (gr < M && gc < DIM) {
                float4 v = *(float4*)&ctile[row * 128 + c4];
                v.x = fmaxf(v.x, 0.f); v.y = fmaxf(v.y, 0.f);
                v.z = fmaxf(v.z, 0.f); v.w = fmaxf(v.w, 0.f);
                if (gc + 3 < DIM) {
                    if constexpr (OUTBF16) {
                        ushort4 o;
                        o.x = f2bf(v.x); o.y = f2bf(v.y);
                        o.z = f2bf(v.z); o.w = f2bf(v.w);
                        *(ushort4*)&houtf[(size_t)gr * DIM + gc] = o;
                    } else {
                        *(float4*)&outf[(size_t)gr * DIM + gc] = v;
                    }
                } else {
                    const float* vp = (const float*)&v;
#pragma unroll
                    for (int q = 0; q < 4; q++) {
                        if (gc + q < DIM) {
                            if constexpr (OUTBF16) houtf[(size_t)gr * DIM + gc + q] = f2bf(vp[q]);
                            else                   outf[(size_t)gr * DIM + gc + q] = vp[q];
                        }
                    }
                }
            }
        }
        __syncthreads();   // ctile reused by next half's load
    }
}

// ---------------- message-sum gather (no self, no epilogue) ----------------
template <bool BF16H>
__global__ __launch_bounds__(256) void gather_msg_kernel(
        const void* __restrict__ h, const float* __restrict__ wexp,
        const uint2* __restrict__ elist2, const uint32_t* __restrict__ rowptr,
        float* __restrict__ msgsum) {
    int n = blockIdx.x;
    int wv = threadIdx.x >> 6, l = threadIdx.x & 63;
    const int D0 = wv * 125;
    const int j0 = l, j1 = l + 64;
    const bool has1 = (j1 < 125);
    const int b0 = j0 / 5;
    const int b1 = j1 / 5;

    __shared__ float hsb[4][2][128];

    uint32_t s = rowptr[n], e = rowptr[n + 1];
    float a0 = 0.f, a1 = 0.f;

    for (uint32_t p = s; p < e; p += 4) {
        const int k = (int)min(4u, e - p);
        uint2 rec[4];
#pragma unroll
        for (int i = 0; i < 4; i++) {
            if (i < k) rec[i] = elist2[p + i];
        }
        float v0[4], v1[4];
#pragma unroll
        for (int i = 0; i < 4; i++) {
            if (i < k) {
                uint32_t src = rec[i].x & 0xFFFFFu;
                if constexpr (BF16H) {
                    const uint16_t* row = (const uint16_t*)h + (size_t)src * DIM + D0;
                    v0[i] = bf2f(row[j0]);
                    v1[i] = has1 ? bf2f(row[j1]) : 0.f;
                } else {
                    const float* row = (const float*)h + (size_t)src * DIM + D0;
                    v0[i] = row[j0];
                    v1[i] = has1 ? row[j1] : 0.f;
                }
            }
        }
#pragma unroll
        for (int i = 0; i < 4; i++) {
            if (i < k) {
                float* hs = hsb[wv][i & 1];
                hs[j0] = v0[i];
                if (has1) hs[j1] = v1[i];
                uint32_t rl = rec[i].x >> 20;
                float inv = __uint_as_float(rec[i].y);
                const float* wbase = wexp + (size_t)rl * (5 * DIM) + D0;
                float w0[5];
#pragma unroll
                for (int q = 0; q < 5; q++) w0[q] = wbase[q * DIM + j0];
                const float* hp0 = hs + b0 * 5;
                float d0 = hp0[0] * w0[0] + hp0[1] * w0[1] + hp0[2] * w0[2]
                         + hp0[3] * w0[3] + hp0[4] * w0[4];
                a0 = fmaf(inv, d0, a0);
                if (has1) {
                    float w1[5];
#pragma unroll
                    for (int q = 0; q < 5; q++) w1[q] = wbase[q * DIM + j1];
                    const float* hp1 = hs + b1 * 5;
                    float d1 = hp1[0] * w1[0] + hp1[1] * w1[1] + hp1[2] * w1[2]
                             + hp1[3] * w1[3] + hp1[4] * w1[4];
                    a1 = fmaf(inv, d1, a1);
                }
            }
        }
    }

    long ob = (long)n * DIM + D0;
    msgsum[ob + j0] = a0;
    if (has1) msgsum[ob + j1] = a1;
}

extern "C" void kernel_launch(void* const* d_in, const int* in_sizes, int n_in,
                              void* d_out, int out_size, void* d_ws, size_t ws_size,
                              hipStream_t stream) {
    const float* x       = nullptr;
    const float* w_rel1  = nullptr;
    const float* w_rel2  = nullptr;
    const float* w_self1 = nullptr;
    const float* w_self2 = nullptr;
    const int*   eidx    = nullptr;
    for (int i = 0; i < n_in; i++) {
        int s = in_sizes[i];
        if (s == N_NODES * DIM) {
            x = (const float*)d_in[i];
        } else if (s == N_REL * 100 * 25) {
            if (!w_rel1) w_rel1 = (const float*)d_in[i];
            else         w_rel2 = (const float*)d_in[i];
        } else if (s == DIM * DIM) {
            if (!w_self1) w_self1 = (const float*)d_in[i];
            else          w_self2 = (const float*)d_in[i];
        } else if (s == N_REL * 2 * N_EDGE) {
            eidx = (const int*)d_in[i];
        }
    }
    float* out = (float*)d_out;

    char* ws = (char*)d_ws;
    uint32_t* cnt_u  = (uint32_t*)(ws + INV_OFF);
    float*    inv    = (float*)(ws + INV_OFF);
    uint32_t* deg    = (uint32_t*)(ws + DEG_OFF);
    uint32_t* rowptr = (uint32_t*)(ws + ROW_OFF);
    uint32_t* scanp  = (uint32_t*)(ws + SCANP_OFF);
    uint32_t* curs   = (uint32_t*)(ws + CURS_OFF);
    uint2*    elist2 = (uint2*)(ws + ELIST_OFF);
    uint16_t* wb1    = (uint16_t*)(ws + WB1_OFF);
    uint16_t* wb2    = (uint16_t*)(ws + WB2_OFF);
    uint16_t* h1     = (uint16_t*)(ws + H1_OFF);
    float*    wexp1  = (float*)(ws + WEXP1_OFF);
    float*    wexp2  = (float*)(ws + WEXP2_OFF);

    const int NB = (N_NODES + 1023) / 1024;

    // CSR build
    zero_kernel<<<(CNT_N + N_NODES + 255) / 256, 256, 0, stream>>>(cnt_u, CNT_N + N_NODES);
    count_kernel<<<(TOT_E + 255) / 256, 256, 0, stream>>>(eidx, cnt_u, deg);
    inv_kernel<<<(CNT_N + 255) / 256, 256, 0, stream>>>(cnt_u, inv);
    scan1_kernel<<<NB, 256, 0, stream>>>(deg, rowptr, scanp);
    scan2_kernel<<<1, 128, 0, stream>>>(scanp, rowptr, NB);
    scan3_kernel<<<NB, 256, 0, stream>>>(rowptr, scanp, curs);
    scatter_kernel<<<(TOT_E + 255) / 256, 256, 0, stream>>>(eidx, inv, curs, elist2);

    // weight prep
    conv_w_kernel<<<512 * 512 / 256, 256, 0, stream>>>(w_self1, wb1);
    conv_w_kernel<<<512 * 512 / 256, 256, 0, stream>>>(w_self2, wb2);
    conv_wexp_kernel<<<(N_REL * 5 * DIM + 255) / 256, 256, 0, stream>>>(w_rel1, wexp1);
    conv_wexp_kernel<<<(N_REL * 5 * DIM + 255) / 256, 256, 0, stream>>>(w_rel2, wexp2);

    // swizzled 1D grid: ceil(782/8)=98 m-locs x 8 xcd x 4 nblk
    const int GB = 98 * 8 * 4;

    // layer 1: msgsum1(d_out) = msgs(x_f32); h1 = relu(x@W1 + msgsum1)  [bf16]
    gather_msg_kernel<false><<<N_NODES, 256, 0, stream>>>(
        x, wexp1, elist2, rowptr, out);
    gemm_fused_kernel<true, true><<<GB, 256, 0, stream>>>(
        x, wb1, out, nullptr, h1, N_NODES);

    // layer 2: msgsum2(d_out) = msgs(h1); out = relu(h1@W2 + msgsum2)  [f32]
    gather_msg_kernel<true><<<N_NODES, 256, 0, stream>>>(
        h1, wexp2, elist2, rowptr, out);
    gemm_fused_kernel<false, false><<<GB, 256, 0, stream>>>(
        h1, wb2, out, out, nullptr, N_NODES);
}

// Round 22
// 1225.998 us; speedup vs baseline: 1.2686x; 1.0448x over previous
//
#include <hip/hip_runtime.h>
#include <hip/hip_bf16.h>
#include <stdint.h>

#define N_NODES 100000
#define N_REL   16
#define N_EDGE  50000
#define DIM     500
#define TOT_E   (N_REL * N_EDGE)      // 800,000
#define CNT_N   (N_REL * N_NODES)     // 1,600,000

// ws layout (8/16B-aligned):
#define INV_OFF    0ull
#define DEG_OFF    6400000ull
#define ROW_OFF    6800000ull
#define SCANP_OFF  7201000ull
#define CURS_OFF   7210000ull
#define ELIST_OFF  7610000ull     // 800k uint2
#define WB1_OFF    14020000ull
#define WB2_OFF    14550000ull
#define H1_OFF     15080000ull    // 50M bf16 h1 -> ends 115,080,000
#define WEXP1_OFF  115080000ull   // 16*5*500 f32 = 160,000 B
#define WEXP2_OFF  115240000ull   // -> end 115,400,000

typedef __attribute__((ext_vector_type(8))) short bf16x8;
typedef __attribute__((ext_vector_type(4))) float f32x4;

// ---------------- threefry2x32, partitionable-mode mask (R8-verified) ----------------
__device__ __forceinline__ uint32_t rotl32(uint32_t x, int d) {
    return (x << d) | (x >> (32 - d));
}
__device__ __forceinline__ bool edge_keep(uint32_t j) {
    uint32_t x0 = 0u, x1 = j;
    const uint32_t ks0 = 0u, ks1 = 42u, ks2 = 0u ^ 42u ^ 0x1BD11BDAu;
    const int RA[4] = {13, 15, 26, 6};
    const int RB[4] = {17, 29, 16, 24};
    x0 += ks0; x1 += ks1;
#pragma unroll
    for (int i = 0; i < 4; i++) { x0 += x1; x1 = rotl32(x1, RA[i]); x1 ^= x0; }
    x0 += ks1; x1 += ks2 + 1u;
#pragma unroll
    for (int i = 0; i < 4; i++) { x0 += x1; x1 = rotl32(x1, RB[i]); x1 ^= x0; }
    x0 += ks2; x1 += ks0 + 2u;
#pragma unroll
    for (int i = 0; i < 4; i++) { x0 += x1; x1 = rotl32(x1, RA[i]); x1 ^= x0; }
    x0 += ks0; x1 += ks1 + 3u;
#pragma unroll
    for (int i = 0; i < 4; i++) { x0 += x1; x1 = rotl32(x1, RB[i]); x1 ^= x0; }
    x0 += ks1; x1 += ks2 + 4u;
#pragma unroll
    for (int i = 0; i < 4; i++) { x0 += x1; x1 = rotl32(x1, RA[i]); x1 ^= x0; }
    x0 += ks2; x1 += ks0 + 5u;
    return ((x0 ^ x1) >> 31) == 0u;
}

__device__ __forceinline__ uint16_t f2bf(float f) {
    uint32_t u = __float_as_uint(f);
    u += 0x7FFFu + ((u >> 16) & 1u);
    return (uint16_t)(u >> 16);
}
__device__ __forceinline__ float bf2f(uint16_t v) {
    return __uint_as_float((uint32_t)v << 16);
}

// ---------------- CSR build ----------------
__global__ __launch_bounds__(256) void zero_kernel(uint32_t* __restrict__ p, int n) {
    int t = blockIdx.x * blockDim.x + threadIdx.x;
    if (t < n) p[t] = 0u;
}

__global__ __launch_bounds__(256) void count_kernel(
        const int* __restrict__ eidx, uint32_t* __restrict__ cnt,
        uint32_t* __restrict__ deg) {
    int tid = blockIdx.x * blockDim.x + threadIdx.x;
    if (tid >= TOT_E) return;
    if (edge_keep((uint32_t)tid)) {
        int r = tid / N_EDGE;
        int e = tid - r * N_EDGE;
        int dst = eidx[(r * 2 + 1) * N_EDGE + e];
        atomicAdd(&cnt[r * N_NODES + dst], 1u);
        atomicAdd(&deg[dst], 1u);
    }
}

__global__ __launch_bounds__(256) void inv_kernel(uint32_t* __restrict__ cnt_u,
                                                  float* __restrict__ inv) {
    int t = blockIdx.x * blockDim.x + threadIdx.x;
    if (t < CNT_N) {
        float c = (float)cnt_u[t];
        inv[t] = 1.0f / fmaxf(c, 1.0f);
    }
}

__global__ __launch_bounds__(256) void scan1_kernel(
        const uint32_t* __restrict__ deg, uint32_t* __restrict__ rowptr,
        uint32_t* __restrict__ scanp) {
    __shared__ uint32_t sh[256];
    int b = blockIdx.x, t = threadIdx.x;
    int base = b * 1024 + t * 4;
    uint32_t x[4];
#pragma unroll
    for (int i = 0; i < 4; i++) x[i] = (base + i < N_NODES) ? deg[base + i] : 0u;
    uint32_t s = x[0] + x[1] + x[2] + x[3];
    sh[t] = s; __syncthreads();
    for (int off = 1; off < 256; off <<= 1) {
        uint32_t v = (t >= off) ? sh[t - off] : 0u;
        __syncthreads();
        sh[t] += v;
        __syncthreads();
    }
    uint32_t run = sh[t] - s;
    if (t == 255) scanp[b] = sh[255];
#pragma unroll
    for (int i = 0; i < 4; i++) {
        if (base + i < N_NODES) rowptr[base + i] = run;
        run += x[i];
    }
}

__global__ __launch_bounds__(128) void scan2_kernel(
        uint32_t* __restrict__ scanp, uint32_t* __restrict__ rowptr, int nb) {
    __shared__ uint32_t sh[128];
    int t = threadIdx.x;
    uint32_t v = (t < nb) ? scanp[t] : 0u;
    sh[t] = v; __syncthreads();
    for (int off = 1; off < 128; off <<= 1) {
        uint32_t u = (t >= off) ? sh[t - off] : 0u;
        __syncthreads();
        sh[t] += u;
        __syncthreads();
    }
    if (t < nb) scanp[t] = sh[t] - v;
    if (t == 127) rowptr[N_NODES] = sh[127];
}

__global__ __launch_bounds__(256) void scan3_kernel(
        uint32_t* __restrict__ rowptr, const uint32_t* __restrict__ scanp,
        uint32_t* __restrict__ curs) {
    int b = blockIdx.x, t = threadIdx.x;
    int base = b * 1024 + t * 4;
    uint32_t off = scanp[b];
#pragma unroll
    for (int i = 0; i < 4; i++) {
        int idx = base + i;
        if (idx < N_NODES) {
            uint32_t v = rowptr[idx] + off;
            rowptr[idx] = v;
            curs[idx] = v;
        }
    }
}

__global__ __launch_bounds__(256) void scatter_kernel(
        const int* __restrict__ eidx, const float* __restrict__ inv,
        uint32_t* __restrict__ curs, uint2* __restrict__ elist2) {
    int tid = blockIdx.x * blockDim.x + threadIdx.x;
    if (tid >= TOT_E) return;
    if (edge_keep((uint32_t)tid)) {
        int r = tid / N_EDGE;
        int e = tid - r * N_EDGE;
        int src = eidx[(r * 2 + 0) * N_EDGE + e];
        int dst = eidx[(r * 2 + 1) * N_EDGE + e];
        uint32_t pos = atomicAdd(&curs[dst], 1u);
        uint2 rec;
        rec.x = (uint32_t)src | ((uint32_t)r << 20);
        rec.y = __float_as_uint(inv[r * N_NODES + dst]);
        elist2[pos] = rec;
    }
}

// ---------------- weight conversions ----------------
__global__ __launch_bounds__(256) void conv_w_kernel(
        const float* __restrict__ W, uint16_t* __restrict__ Bt) {
    int idx = blockIdx.x * 256 + threadIdx.x;
    int n = idx >> 9, k = idx & 511;
    float v = (n < DIM && k < DIM) ? W[k * DIM + n] : 0.f;
    Bt[idx] = f2bf(v);
}

// wexp[r][i][j] = w_rel[r][j/5][i][j%5]  (16 x 5 x 500 f32): lane-j coalesced
__global__ __launch_bounds__(256) void conv_wexp_kernel(
        const float* __restrict__ W, float* __restrict__ wexp) {
    int idx = blockIdx.x * 256 + threadIdx.x;
    if (idx >= N_REL * 5 * DIM) return;
    int r = idx / (5 * DIM);
    int rem = idx - r * 5 * DIM;
    int i = rem / DIM;
    int j = rem - i * DIM;
    wexp[idx] = W[r * 2500 + (j / 5) * 25 + i * 5 + (j % 5)];
}

// ---------------- plain MFMA bf16 GEMM 128x128, XCD-swizzled grid ----------------
// R18's fast kernel + R20's proven m-group XCD swizzle (A-panel re-reads hit
// the same XCD's L2). AF32: stage A from f32 with in-stage bf16 convert
// (removes conv_x for layer 1). Plain scattered C store (R18-proven).
template <bool AF32>
__global__ __launch_bounds__(256) void gemm_mfma128_kernel(
        const void* __restrict__ A, const uint16_t* __restrict__ Bt,
        float* __restrict__ C, int M) {
    int bid = blockIdx.x;
    int xcd = bid & 7;
    int slot = bid >> 3;
    int nblk = slot & 3;
    int mloc = slot >> 2;
    int mblk = mloc * 8 + xcd;
    if (mblk >= (N_NODES + 127) / 128) return;
    int m0 = mblk * 128;
    int n0 = nblk * 128;

    __shared__ uint16_t As[128][72];
    __shared__ uint16_t Bs[128][72];
    int t = threadIdx.x;
    int wave = t >> 6, lane = t & 63;
    int wm = wave >> 1, wn = wave & 1;
    f32x4 acc[4][4] = {};

    for (int k0 = 0; k0 < 512; k0 += 64) {
#pragma unroll
        for (int i = 0; i < 4; i++) {
            int c = t * 4 + i;             // 0..1023
            int row = c >> 3;              // 0..127
            int col = (c & 7) * 8;         // 0..56
            int gm = m0 + row, gk = k0 + col;
            uint16_t* dst = &As[row][col];
            if constexpr (AF32) {
                const float* Af = (const float*)A;
                if (gm < M && gk + 7 < DIM) {
                    float4 p0 = *(const float4*)&Af[(size_t)gm * DIM + gk];
                    float4 p1 = *(const float4*)&Af[(size_t)gm * DIM + gk + 4];
                    dst[0] = f2bf(p0.x); dst[1] = f2bf(p0.y);
                    dst[2] = f2bf(p0.z); dst[3] = f2bf(p0.w);
                    dst[4] = f2bf(p1.x); dst[5] = f2bf(p1.y);
                    dst[6] = f2bf(p1.z); dst[7] = f2bf(p1.w);
                } else {
#pragma unroll
                    for (int q = 0; q < 8; q++)
                        dst[q] = (gm < M && gk + q < DIM)
                                     ? f2bf(Af[(size_t)gm * DIM + gk + q]) : (uint16_t)0;
                }
            } else {
                const uint16_t* Ab = (const uint16_t*)A;
                if (gm < M && gk + 7 < DIM) {
                    *(bf16x8*)dst = *(const bf16x8*)&Ab[(size_t)gm * DIM + gk];
                } else {
#pragma unroll
                    for (int q = 0; q < 8; q++)
                        dst[q] = (gm < M && gk + q < DIM) ? Ab[(size_t)gm * DIM + gk + q]
                                                          : (uint16_t)0;
                }
            }
            *(bf16x8*)&Bs[row][col] =
                *(const bf16x8*)&Bt[(size_t)(n0 + row) * 512 + k0 + col];
        }
        __syncthreads();

        int ks = (lane >> 4) * 8;
        int rl = lane & 15;
        bf16x8 af[4][2], bfr[4][2];
#pragma unroll
        for (int mt = 0; mt < 4; mt++) {
            af[mt][0] = *(const bf16x8*)&As[wm * 64 + mt * 16 + rl][ks];
            af[mt][1] = *(const bf16x8*)&As[wm * 64 + mt * 16 + rl][32 + ks];
        }
#pragma unroll
        for (int nt = 0; nt < 4; nt++) {
            bfr[nt][0] = *(const bf16x8*)&Bs[wn * 64 + nt * 16 + rl][ks];
            bfr[nt][1] = *(const bf16x8*)&Bs[wn * 64 + nt * 16 + rl][32 + ks];
        }
#pragma unroll
        for (int mt = 0; mt < 4; mt++)
#pragma unroll
            for (int nt = 0; nt < 4; nt++) {
                acc[mt][nt] = __builtin_amdgcn_mfma_f32_16x16x32_bf16(
                    af[mt][0], bfr[nt][0], acc[mt][nt], 0, 0, 0);
                acc[mt][nt] = __builtin_amdgcn_mfma_f32_16x16x32_bf16(
                    af[mt][1], bfr[nt][1], acc[mt][nt], 0, 0, 0);
            }
        __syncthreads();
    }

    // C/D layout (m89-verified): col = lane&15, row = (lane>>4)*4 + reg
    int cl = lane & 15;
    int rq = (lane >> 4) << 2;
#pragma unroll
    for (int mt = 0; mt < 4; mt++) {
        int rbase = m0 + wm * 64 + mt * 16 + rq;
#pragma unroll
        for (int nt = 0; nt < 4; nt++) {
            int col = n0 + wn * 64 + nt * 16 + cl;
            if (col < DIM) {
#pragma unroll
                for (int q = 0; q < 4; q++) {
                    int rr = rbase + q;
                    if (rr < M) C[(size_t)rr * DIM + col] = acc[mt][nt][q];
                }
            }
        }
    }
}

// ---------------- R18 gather: msgs + self + relu epilogue (361 us known) ----------------
template <bool BF16H, bool OUT_BF16>
__global__ __launch_bounds__(256) void gather_kernel(
        const void* __restrict__ h, const float* __restrict__ wexp,
        const uint2* __restrict__ elist2, const uint32_t* __restrict__ rowptr,
        const float* __restrict__ self_in, float* __restrict__ out_f32,
        uint16_t* __restrict__ out_bf16) {
    int n = blockIdx.x;
    int wv = threadIdx.x >> 6, l = threadIdx.x & 63;
    const int D0 = wv * 125;
    const int j0 = l, j1 = l + 64;
    const bool has1 = (j1 < 125);
    const int b0 = j0 / 5;
    const int b1 = j1 / 5;

    __shared__ float hsb[4][2][128];

    // self prefetch: independent of edges -> overlaps the edge chains
    long ob = (long)n * DIM + D0;
    float self0 = self_in[ob + j0];
    float self1 = has1 ? self_in[ob + j1] : 0.f;

    uint32_t s = rowptr[n], e = rowptr[n + 1];
    float a0 = 0.f, a1 = 0.f;

    for (uint32_t p = s; p < e; p += 4) {
        const int k = (int)min(4u, e - p);
        uint2 rec[4];
#pragma unroll
        for (int i = 0; i < 4; i++) {
            if (i < k) rec[i] = elist2[p + i];
        }
        float v0[4], v1[4];
#pragma unroll
        for (int i = 0; i < 4; i++) {
            if (i < k) {
                uint32_t src = rec[i].x & 0xFFFFFu;
                if constexpr (BF16H) {
                    const uint16_t* row = (const uint16_t*)h + (size_t)src * DIM + D0;
                    v0[i] = bf2f(row[j0]);
                    v1[i] = has1 ? bf2f(row[j1]) : 0.f;
                } else {
                    const float* row = (const float*)h + (size_t)src * DIM + D0;
                    v0[i] = row[j0];
                    v1[i] = has1 ? row[j1] : 0.f;
                }
            }
        }
#pragma unroll
        for (int i = 0; i < 4; i++) {
            if (i < k) {
                float* hs = hsb[wv][i & 1];
                hs[j0] = v0[i];
                if (has1) hs[j1] = v1[i];
                uint32_t rl = rec[i].x >> 20;
                float inv = __uint_as_float(rec[i].y);
                const float* wbase = wexp + (size_t)rl * (5 * DIM) + D0;
                float w0[5];
#pragma unroll
                for (int q = 0; q < 5; q++) w0[q] = wbase[q * DIM + j0];
                const float* hp0 = hs + b0 * 5;
                float d0 = hp0[0] * w0[0] + hp0[1] * w0[1] + hp0[2] * w0[2]
                         + hp0[3] * w0[3] + hp0[4] * w0[4];
                a0 = fmaf(inv, d0, a0);
                if (has1) {
                    float w1[5];
#pragma unroll
                    for (int q = 0; q < 5; q++) w1[q] = wbase[q * DIM + j1];
                    const float* hp1 = hs + b1 * 5;
                    float d1 = hp1[0] * w1[0] + hp1[1] * w1[1] + hp1[2] * w1[2]
                             + hp1[3] * w1[3] + hp1[4] * w1[4];
                    a1 = fmaf(inv, d1, a1);
                }
            }
        }
    }

    {
        float v = fmaxf(self0 + a0, 0.f);
        if (OUT_BF16) out_bf16[ob + j0] = f2bf(v);
        else          out_f32[ob + j0] = v;
    }
    if (has1) {
        float v = fmaxf(self1 + a1, 0.f);
        if (OUT_BF16) out_bf16[ob + j1] = f2bf(v);
        else          out_f32[ob + j1] = v;
    }
}

extern "C" void kernel_launch(void* const* d_in, const int* in_sizes, int n_in,
                              void* d_out, int out_size, void* d_ws, size_t ws_size,
                              hipStream_t stream) {
    const float* x       = nullptr;
    const float* w_rel1  = nullptr;
    const float* w_rel2  = nullptr;
    const float* w_self1 = nullptr;
    const float* w_self2 = nullptr;
    const int*   eidx    = nullptr;
    for (int i = 0; i < n_in; i++) {
        int s = in_sizes[i];
        if (s == N_NODES * DIM) {
            x = (const float*)d_in[i];
        } else if (s == N_REL * 100 * 25) {
            if (!w_rel1) w_rel1 = (const float*)d_in[i];
            else         w_rel2 = (const float*)d_in[i];
        } else if (s == DIM * DIM) {
            if (!w_self1) w_self1 = (const float*)d_in[i];
            else          w_self2 = (const float*)d_in[i];
        } else if (s == N_REL * 2 * N_EDGE) {
            eidx = (const int*)d_in[i];
        }
    }
    float* out = (float*)d_out;

    char* ws = (char*)d_ws;
    uint32_t* cnt_u  = (uint32_t*)(ws + INV_OFF);
    float*    inv    = (float*)(ws + INV_OFF);
    uint32_t* deg    = (uint32_t*)(ws + DEG_OFF);
    uint32_t* rowptr = (uint32_t*)(ws + ROW_OFF);
    uint32_t* scanp  = (uint32_t*)(ws + SCANP_OFF);
    uint32_t* curs   = (uint32_t*)(ws + CURS_OFF);
    uint2*    elist2 = (uint2*)(ws + ELIST_OFF);
    uint16_t* wb1    = (uint16_t*)(ws + WB1_OFF);
    uint16_t* wb2    = (uint16_t*)(ws + WB2_OFF);
    uint16_t* h1     = (uint16_t*)(ws + H1_OFF);
    float*    wexp1  = (float*)(ws + WEXP1_OFF);
    float*    wexp2  = (float*)(ws + WEXP2_OFF);

    const int NB = (N_NODES + 1023) / 1024;

    // CSR build
    zero_kernel<<<(CNT_N + N_NODES + 255) / 256, 256, 0, stream>>>(cnt_u, CNT_N + N_NODES);
    count_kernel<<<(TOT_E + 255) / 256, 256, 0, stream>>>(eidx, cnt_u, deg);
    inv_kernel<<<(CNT_N + 255) / 256, 256, 0, stream>>>(cnt_u, inv);
    scan1_kernel<<<NB, 256, 0, stream>>>(deg, rowptr, scanp);
    scan2_kernel<<<1, 128, 0, stream>>>(scanp, rowptr, NB);
    scan3_kernel<<<NB, 256, 0, stream>>>(rowptr, scanp, curs);
    scatter_kernel<<<(TOT_E + 255) / 256, 256, 0, stream>>>(eidx, inv, curs, elist2);

    // weight prep (no conv_x: layer-1 GEMM stages straight from f32 x)
    conv_w_kernel<<<512 * 512 / 256, 256, 0, stream>>>(w_self1, wb1);
    conv_w_kernel<<<512 * 512 / 256, 256, 0, stream>>>(w_self2, wb2);
    conv_wexp_kernel<<<(N_REL * 5 * DIM + 255) / 256, 256, 0, stream>>>(w_rel1, wexp1);
    conv_wexp_kernel<<<(N_REL * 5 * DIM + 255) / 256, 256, 0, stream>>>(w_rel2, wexp2);

    // swizzled 1D grid: ceil(782/8)=98 m-locs x 8 xcd x 4 nblk
    const int GB = 98 * 8 * 4;

    // layer 1: out(f32) = x @ w_self1 (MFMA, AF32 staging);
    //          h1 = relu(out + msgs(x_f32))  [bf16]
    gemm_mfma128_kernel<true><<<GB, 256, 0, stream>>>(x, wb1, out, N_NODES);
    gather_kernel<false, true><<<N_NODES, 256, 0, stream>>>(
        x, wexp1, elist2, rowptr, out, nullptr, h1);

    // layer 2: out(f32) = h1 @ w_self2 (MFMA); out = relu(out + msgs(h1))  [f32]
    gemm_mfma128_kernel<false><<<GB, 256, 0, stream>>>(h1, wb2, out, N_NODES);
    gather_kernel<true, false><<<N_NODES, 256, 0, stream>>>(
        h1, wexp2, elist2, rowptr, out, out, nullptr);
}

// Round 23
// 1185.714 us; speedup vs baseline: 1.3117x; 1.0340x over previous
//
#include <hip/hip_runtime.h>
#include <hip/hip_bf16.h>
#include <stdint.h>

#define N_NODES 100000
#define N_REL   16
#define N_EDGE  50000
#define DIM     500
#define TOT_E   (N_REL * N_EDGE)      // 800,000
#define CNT_N   (N_REL * N_NODES)     // 1,600,000

// ws layout (8/16B-aligned):
#define INV_OFF    0ull
#define DEG_OFF    6400000ull
#define ROW_OFF    6800000ull
#define SCANP_OFF  7201000ull
#define CURS_OFF   7210000ull
#define ELIST_OFF  7610000ull     // 800k uint2
#define WB1_OFF    14020000ull
#define WB2_OFF    14550000ull
#define H1_OFF     15080000ull    // 50M bf16 (x_bf16 then h1) -> ends 115,080,000
#define WEXP1_OFF  115080000ull   // 16*5*500 f32 = 160,000 B
#define WEXP2_OFF  115240000ull   // -> end 115,400,000

typedef __attribute__((ext_vector_type(8))) short bf16x8;
typedef __attribute__((ext_vector_type(4))) float f32x4;

// ---------------- threefry2x32, partitionable-mode mask (R8-verified) ----------------
__device__ __forceinline__ uint32_t rotl32(uint32_t x, int d) {
    return (x << d) | (x >> (32 - d));
}
__device__ __forceinline__ bool edge_keep(uint32_t j) {
    uint32_t x0 = 0u, x1 = j;
    const uint32_t ks0 = 0u, ks1 = 42u, ks2 = 0u ^ 42u ^ 0x1BD11BDAu;
    const int RA[4] = {13, 15, 26, 6};
    const int RB[4] = {17, 29, 16, 24};
    x0 += ks0; x1 += ks1;
#pragma unroll
    for (int i = 0; i < 4; i++) { x0 += x1; x1 = rotl32(x1, RA[i]); x1 ^= x0; }
    x0 += ks1; x1 += ks2 + 1u;
#pragma unroll
    for (int i = 0; i < 4; i++) { x0 += x1; x1 = rotl32(x1, RB[i]); x1 ^= x0; }
    x0 += ks2; x1 += ks0 + 2u;
#pragma unroll
    for (int i = 0; i < 4; i++) { x0 += x1; x1 = rotl32(x1, RA[i]); x1 ^= x0; }
    x0 += ks0; x1 += ks1 + 3u;
#pragma unroll
    for (int i = 0; i < 4; i++) { x0 += x1; x1 = rotl32(x1, RB[i]); x1 ^= x0; }
    x0 += ks1; x1 += ks2 + 4u;
#pragma unroll
    for (int i = 0; i < 4; i++) { x0 += x1; x1 = rotl32(x1, RA[i]); x1 ^= x0; }
    x0 += ks2; x1 += ks0 + 5u;
    return ((x0 ^ x1) >> 31) == 0u;
}

__device__ __forceinline__ uint16_t f2bf(float f) {
    uint32_t u = __float_as_uint(f);
    u += 0x7FFFu + ((u >> 16) & 1u);
    return (uint16_t)(u >> 16);
}
__device__ __forceinline__ float bf2f(uint16_t v) {
    return __uint_as_float((uint32_t)v << 16);
}

// ---------------- CSR build ----------------
__global__ __launch_bounds__(256) void zero_kernel(uint32_t* __restrict__ p, int n) {
    int t = blockIdx.x * blockDim.x + threadIdx.x;
    if (t < n) p[t] = 0u;
}

__global__ __launch_bounds__(256) void count_kernel(
        const int* __restrict__ eidx, uint32_t* __restrict__ cnt,
        uint32_t* __restrict__ deg) {
    int tid = blockIdx.x * blockDim.x + threadIdx.x;
    if (tid >= TOT_E) return;
    if (edge_keep((uint32_t)tid)) {
        int r = tid / N_EDGE;
        int e = tid - r * N_EDGE;
        int dst = eidx[(r * 2 + 1) * N_EDGE + e];
        atomicAdd(&cnt[r * N_NODES + dst], 1u);
        atomicAdd(&deg[dst], 1u);
    }
}

__global__ __launch_bounds__(256) void inv_kernel(uint32_t* __restrict__ cnt_u,
                                                  float* __restrict__ inv) {
    int t = blockIdx.x * blockDim.x + threadIdx.x;
    if (t < CNT_N) {
        float c = (float)cnt_u[t];
        inv[t] = 1.0f / fmaxf(c, 1.0f);
    }
}

__global__ __launch_bounds__(256) void scan1_kernel(
        const uint32_t* __restrict__ deg, uint32_t* __restrict__ rowptr,
        uint32_t* __restrict__ scanp) {
    __shared__ uint32_t sh[256];
    int b = blockIdx.x, t = threadIdx.x;
    int base = b * 1024 + t * 4;
    uint32_t x[4];
#pragma unroll
    for (int i = 0; i < 4; i++) x[i] = (base + i < N_NODES) ? deg[base + i] : 0u;
    uint32_t s = x[0] + x[1] + x[2] + x[3];
    sh[t] = s; __syncthreads();
    for (int off = 1; off < 256; off <<= 1) {
        uint32_t v = (t >= off) ? sh[t - off] : 0u;
        __syncthreads();
        sh[t] += v;
        __syncthreads();
    }
    uint32_t run = sh[t] - s;
    if (t == 255) scanp[b] = sh[255];
#pragma unroll
    for (int i = 0; i < 4; i++) {
        if (base + i < N_NODES) rowptr[base + i] = run;
        run += x[i];
    }
}

__global__ __launch_bounds__(128) void scan2_kernel(
        uint32_t* __restrict__ scanp, uint32_t* __restrict__ rowptr, int nb) {
    __shared__ uint32_t sh[128];
    int t = threadIdx.x;
    uint32_t v = (t < nb) ? scanp[t] : 0u;
    sh[t] = v; __syncthreads();
    for (int off = 1; off < 128; off <<= 1) {
        uint32_t u = (t >= off) ? sh[t - off] : 0u;
        __syncthreads();
        sh[t] += u;
        __syncthreads();
    }
    if (t < nb) scanp[t] = sh[t] - v;
    if (t == 127) rowptr[N_NODES] = sh[127];
}

__global__ __launch_bounds__(256) void scan3_kernel(
        uint32_t* __restrict__ rowptr, const uint32_t* __restrict__ scanp,
        uint32_t* __restrict__ curs) {
    int b = blockIdx.x, t = threadIdx.x;
    int base = b * 1024 + t * 4;
    uint32_t off = scanp[b];
#pragma unroll
    for (int i = 0; i < 4; i++) {
        int idx = base + i;
        if (idx < N_NODES) {
            uint32_t v = rowptr[idx] + off;
            rowptr[idx] = v;
            curs[idx] = v;
        }
    }
}

__global__ __launch_bounds__(256) void scatter_kernel(
        const int* __restrict__ eidx, const float* __restrict__ inv,
        uint32_t* __restrict__ curs, uint2* __restrict__ elist2) {
    int tid = blockIdx.x * blockDim.x + threadIdx.x;
    if (tid >= TOT_E) return;
    if (edge_keep((uint32_t)tid)) {
        int r = tid / N_EDGE;
        int e = tid - r * N_EDGE;
        int src = eidx[(r * 2 + 0) * N_EDGE + e];
        int dst = eidx[(r * 2 + 1) * N_EDGE + e];
        uint32_t pos = atomicAdd(&curs[dst], 1u);
        uint2 rec;
        rec.x = (uint32_t)src | ((uint32_t)r << 20);
        rec.y = __float_as_uint(inv[r * N_NODES + dst]);
        elist2[pos] = rec;
    }
}

// ---------------- conversions ----------------
__global__ __launch_bounds__(256) void conv_x_kernel(
        const float4* __restrict__ in, ushort4* __restrict__ outp, int n4) {
    int t = blockIdx.x * blockDim.x + threadIdx.x;
    if (t >= n4) return;
    float4 v = in[t];
    ushort4 o;
    o.x = f2bf(v.x); o.y = f2bf(v.y); o.z = f2bf(v.z); o.w = f2bf(v.w);
    outp[t] = o;
}

__global__ __launch_bounds__(256) void conv_w_kernel(
        const float* __restrict__ W, uint16_t* __restrict__ Bt) {
    int idx = blockIdx.x * 256 + threadIdx.x;
    int n = idx >> 9, k = idx & 511;
    float v = (n < DIM && k < DIM) ? W[k * DIM + n] : 0.f;
    Bt[idx] = f2bf(v);
}

// wexp[r][i][j] = w_rel[r][j/5][i][j%5]  (16 x 5 x 500 f32): lane-j coalesced
__global__ __launch_bounds__(256) void conv_wexp_kernel(
        const float* __restrict__ W, float* __restrict__ wexp) {
    int idx = blockIdx.x * 256 + threadIdx.x;
    if (idx >= N_REL * 5 * DIM) return;
    int r = idx / (5 * DIM);
    int rem = idx - r * 5 * DIM;
    int i = rem / DIM;
    int j = rem - i * DIM;
    wexp[idx] = W[r * 2500 + (j / 5) * 25 + i * 5 + (j % 5)];
}

// ---------------- plain MFMA bf16 GEMM 128x128, XCD-swizzled grid ----------------
// R18-proven kernel (bf16 A staging) + R20-proven m-group XCD swizzle.
__global__ __launch_bounds__(256) void gemm_mfma128_kernel(
        const uint16_t* __restrict__ A, const uint16_t* __restrict__ Bt,
        float* __restrict__ C, int M) {
    int bid = blockIdx.x;
    int xcd = bid & 7;
    int slot = bid >> 3;
    int nblk = slot & 3;
    int mloc = slot >> 2;
    int mblk = mloc * 8 + xcd;
    if (mblk >= (N_NODES + 127) / 128) return;
    int m0 = mblk * 128;
    int n0 = nblk * 128;

    __shared__ uint16_t As[128][72];
    __shared__ uint16_t Bs[128][72];
    int t = threadIdx.x;
    int wave = t >> 6, lane = t & 63;
    int wm = wave >> 1, wn = wave & 1;
    f32x4 acc[4][4] = {};

    for (int k0 = 0; k0 < 512; k0 += 64) {
#pragma unroll
        for (int i = 0; i < 4; i++) {
            int c = t * 4 + i;             // 0..1023
            int row = c >> 3;              // 0..127
            int col = (c & 7) * 8;         // 0..56
            int gm = m0 + row, gk = k0 + col;
            uint16_t* dst = &As[row][col];
            if (gm < M && gk + 7 < DIM) {
                *(bf16x8*)dst = *(const bf16x8*)&A[(size_t)gm * DIM + gk];
            } else {
#pragma unroll
                for (int q = 0; q < 8; q++)
                    dst[q] = (gm < M && gk + q < DIM) ? A[(size_t)gm * DIM + gk + q]
                                                      : (uint16_t)0;
            }
            *(bf16x8*)&Bs[row][col] =
                *(const bf16x8*)&Bt[(size_t)(n0 + row) * 512 + k0 + col];
        }
        __syncthreads();

        int ks = (lane >> 4) * 8;
        int rl = lane & 15;
        bf16x8 af[4][2], bfr[4][2];
#pragma unroll
        for (int mt = 0; mt < 4; mt++) {
            af[mt][0] = *(const bf16x8*)&As[wm * 64 + mt * 16 + rl][ks];
            af[mt][1] = *(const bf16x8*)&As[wm * 64 + mt * 16 + rl][32 + ks];
        }
#pragma unroll
        for (int nt = 0; nt < 4; nt++) {
            bfr[nt][0] = *(const bf16x8*)&Bs[wn * 64 + nt * 16 + rl][ks];
            bfr[nt][1] = *(const bf16x8*)&Bs[wn * 64 + nt * 16 + rl][32 + ks];
        }
#pragma unroll
        for (int mt = 0; mt < 4; mt++)
#pragma unroll
            for (int nt = 0; nt < 4; nt++) {
                acc[mt][nt] = __builtin_amdgcn_mfma_f32_16x16x32_bf16(
                    af[mt][0], bfr[nt][0], acc[mt][nt], 0, 0, 0);
                acc[mt][nt] = __builtin_amdgcn_mfma_f32_16x16x32_bf16(
                    af[mt][1], bfr[nt][1], acc[mt][nt], 0, 0, 0);
            }
        __syncthreads();
    }

    int cl = lane & 15;
    int rq = (lane >> 4) << 2;
#pragma unroll
    for (int mt = 0; mt < 4; mt++) {
        int rbase = m0 + wm * 64 + mt * 16 + rq;
#pragma unroll
        for (int nt = 0; nt < 4; nt++) {
            int col = n0 + wn * 64 + nt * 16 + cl;
            if (col < DIM) {
#pragma unroll
                for (int q = 0; q < 4; q++) {
                    int rr = rbase + q;
                    if (rr < M) C[(size_t)rr * DIM + col] = acc[mt][nt][q];
                }
            }
        }
    }
}

// ---------------- TWO-NODE gather: doubled memory-chain ILP per wave ----------------
// Block b serves nodes 2b and 2b+1; wave wv owns 125-dim chunk wv of BOTH.
// Per batch: all recs (A+B) issue, then all row slices (A+B), then compute A,
// compute B (separate LDS buffers hsb[wv][0/1]). Per-node arithmetic order is
// identical to R18 (bit-identical results). N_NODES even -> n1 always valid.
template <bool BF16H, bool OUT_BF16>
__global__ __launch_bounds__(256) void gather_kernel(
        const void* __restrict__ h, const float* __restrict__ wexp,
        const uint2* __restrict__ elist2, const uint32_t* __restrict__ rowptr,
        const float* __restrict__ self_in, float* __restrict__ out_f32,
        uint16_t* __restrict__ out_bf16) {
    int n0 = blockIdx.x * 2;
    int n1 = n0 + 1;
    int wv = threadIdx.x >> 6, l = threadIdx.x & 63;
    const int D0 = wv * 125;
    const int j0 = l, j1 = l + 64;
    const bool has1 = (j1 < 125);
    const int b0 = j0 / 5;
    const int b1 = j1 / 5;

    __shared__ float hsb[4][2][128];
    float* hsA = hsb[wv][0];
    float* hsB = hsb[wv][1];

    long obA = (long)n0 * DIM + D0;
    long obB = (long)n1 * DIM + D0;
    float selfA0 = self_in[obA + j0];
    float selfA1 = has1 ? self_in[obA + j1] : 0.f;
    float selfB0 = self_in[obB + j0];
    float selfB1 = has1 ? self_in[obB + j1] : 0.f;

    uint32_t pA = rowptr[n0], eA = rowptr[n0 + 1];
    uint32_t pB = rowptr[n1], eB = rowptr[n1 + 1];
    float aA0 = 0.f, aA1 = 0.f, aB0 = 0.f, aB1 = 0.f;

    while (pA < eA || pB < eB) {
        const int kA = (int)min(4u, eA - pA);   // 0 when drained (eA-pA==0)
        const int kB = (int)min(4u, eB - pB);

        // stage 1: ALL rec loads (A then B) issue together
        uint2 recA[4], recB[4];
#pragma unroll
        for (int i = 0; i < 4; i++) { if (i < kA) recA[i] = elist2[pA + i]; }
#pragma unroll
        for (int i = 0; i < 4; i++) { if (i < kB) recB[i] = elist2[pB + i]; }

        // stage 2: ALL row-slice loads (A then B) issue together
        float vA0[4], vA1[4], vB0[4], vB1[4];
#pragma unroll
        for (int i = 0; i < 4; i++) {
            if (i < kA) {
                uint32_t src = recA[i].x & 0xFFFFFu;
                if constexpr (BF16H) {
                    const uint16_t* row = (const uint16_t*)h + (size_t)src * DIM + D0;
                    vA0[i] = bf2f(row[j0]);
                    vA1[i] = has1 ? bf2f(row[j1]) : 0.f;
                } else {
                    const float* row = (const float*)h + (size_t)src * DIM + D0;
                    vA0[i] = row[j0];
                    vA1[i] = has1 ? row[j1] : 0.f;
                }
            }
        }
#pragma unroll
        for (int i = 0; i < 4; i++) {
            if (i < kB) {
                uint32_t src = recB[i].x & 0xFFFFFu;
                if constexpr (BF16H) {
                    const uint16_t* row = (const uint16_t*)h + (size_t)src * DIM + D0;
                    vB0[i] = bf2f(row[j0]);
                    vB1[i] = has1 ? bf2f(row[j1]) : 0.f;
                } else {
                    const float* row = (const float*)h + (size_t)src * DIM + D0;
                    vB0[i] = row[j0];
                    vB1[i] = has1 ? row[j1] : 0.f;
                }
            }
        }

        // stage 3: compute A, then B
#pragma unroll
        for (int i = 0; i < 4; i++) {
            if (i < kA) {
                hsA[j0] = vA0[i];
                if (has1) hsA[j1] = vA1[i];
                uint32_t rl = recA[i].x >> 20;
                float inv = __uint_as_float(recA[i].y);
                const float* wbase = wexp + (size_t)rl * (5 * DIM) + D0;
                float w0[5];
#pragma unroll
                for (int q = 0; q < 5; q++) w0[q] = wbase[q * DIM + j0];
                const float* hp0 = hsA + b0 * 5;
                float d0 = hp0[0] * w0[0] + hp0[1] * w0[1] + hp0[2] * w0[2]
                         + hp0[3] * w0[3] + hp0[4] * w0[4];
                aA0 = fmaf(inv, d0, aA0);
                if (has1) {
                    float w1[5];
#pragma unroll
                    for (int q = 0; q < 5; q++) w1[q] = wbase[q * DIM + j1];
                    const float* hp1 = hsA + b1 * 5;
                    float d1 = hp1[0] * w1[0] + hp1[1] * w1[1] + hp1[2] * w1[2]
                             + hp1[3] * w1[3] + hp1[4] * w1[4];
                    aA1 = fmaf(inv, d1, aA1);
                }
            }
        }
#pragma unroll
        for (int i = 0; i < 4; i++) {
            if (i < kB) {
                hsB[j0] = vB0[i];
                if (has1) hsB[j1] = vB1[i];
                uint32_t rl = recB[i].x >> 20;
                float inv = __uint_as_float(recB[i].y);
                const float* wbase = wexp + (size_t)rl * (5 * DIM) + D0;
                float w0[5];
#pragma unroll
                for (int q = 0; q < 5; q++) w0[q] = wbase[q * DIM + j0];
                const float* hp0 = hsB + b0 * 5;
                float d0 = hp0[0] * w0[0] + hp0[1] * w0[1] + hp0[2] * w0[2]
                         + hp0[3] * w0[3] + hp0[4] * w0[4];
                aB0 = fmaf(inv, d0, aB0);
                if (has1) {
                    float w1[5];
#pragma unroll
                    for (int q = 0; q < 5; q++) w1[q] = wbase[q * DIM + j1];
                    const float* hp1 = hsB + b1 * 5;
                    float d1 = hp1[0] * w1[0] + hp1[1] * w1[1] + hp1[2] * w1[2]
                             + hp1[3] * w1[3] + hp1[4] * w1[4];
                    aB1 = fmaf(inv, d1, aB1);
                }
            }
        }

        pA += kA;
        pB += kB;
    }

    {
        float v = fmaxf(selfA0 + aA0, 0.f);
        if (OUT_BF16) out_bf16[obA + j0] = f2bf(v);
        else          out_f32[obA + j0] = v;
    }
    if (has1) {
        float v = fmaxf(selfA1 + aA1, 0.f);
        if (OUT_BF16) out_bf16[obA + j1] = f2bf(v);
        else          out_f32[obA + j1] = v;
    }
    {
        float v = fmaxf(selfB0 + aB0, 0.f);
        if (OUT_BF16) out_bf16[obB + j0] = f2bf(v);
        else          out_f32[obB + j0] = v;
    }
    if (has1) {
        float v = fmaxf(selfB1 + aB1, 0.f);
        if (OUT_BF16) out_bf16[obB + j1] = f2bf(v);
        else          out_f32[obB + j1] = v;
    }
}

extern "C" void kernel_launch(void* const* d_in, const int* in_sizes, int n_in,
                              void* d_out, int out_size, void* d_ws, size_t ws_size,
                              hipStream_t stream) {
    const float* x       = nullptr;
    const float* w_rel1  = nullptr;
    const float* w_rel2  = nullptr;
    const float* w_self1 = nullptr;
    const float* w_self2 = nullptr;
    const int*   eidx    = nullptr;
    for (int i = 0; i < n_in; i++) {
        int s = in_sizes[i];
        if (s == N_NODES * DIM) {
            x = (const float*)d_in[i];
        } else if (s == N_REL * 100 * 25) {
            if (!w_rel1) w_rel1 = (const float*)d_in[i];
            else         w_rel2 = (const float*)d_in[i];
        } else if (s == DIM * DIM) {
            if (!w_self1) w_self1 = (const float*)d_in[i];
            else          w_self2 = (const float*)d_in[i];
        } else if (s == N_REL * 2 * N_EDGE) {
            eidx = (const int*)d_in[i];
        }
    }
    float* out = (float*)d_out;

    char* ws = (char*)d_ws;
    uint32_t* cnt_u  = (uint32_t*)(ws + INV_OFF);
    float*    inv    = (float*)(ws + INV_OFF);
    uint32_t* deg    = (uint32_t*)(ws + DEG_OFF);
    uint32_t* rowptr = (uint32_t*)(ws + ROW_OFF);
    uint32_t* scanp  = (uint32_t*)(ws + SCANP_OFF);
    uint32_t* curs   = (uint32_t*)(ws + CURS_OFF);
    uint2*    elist2 = (uint2*)(ws + ELIST_OFF);
    uint16_t* wb1    = (uint16_t*)(ws + WB1_OFF);
    uint16_t* wb2    = (uint16_t*)(ws + WB2_OFF);
    uint16_t* h1     = (uint16_t*)(ws + H1_OFF);
    float*    wexp1  = (float*)(ws + WEXP1_OFF);
    float*    wexp2  = (float*)(ws + WEXP2_OFF);

    const int NB = (N_NODES + 1023) / 1024;

    // CSR build
    zero_kernel<<<(CNT_N + N_NODES + 255) / 256, 256, 0, stream>>>(cnt_u, CNT_N + N_NODES);
    count_kernel<<<(TOT_E + 255) / 256, 256, 0, stream>>>(eidx, cnt_u, deg);
    inv_kernel<<<(CNT_N + 255) / 256, 256, 0, stream>>>(cnt_u, inv);
    scan1_kernel<<<NB, 256, 0, stream>>>(deg, rowptr, scanp);
    scan2_kernel<<<1, 128, 0, stream>>>(scanp, rowptr, NB);
    scan3_kernel<<<NB, 256, 0, stream>>>(rowptr, scanp, curs);
    scatter_kernel<<<(TOT_E + 255) / 256, 256, 0, stream>>>(eidx, inv, curs, elist2);

    // conversions / weight prep
    conv_x_kernel<<<(N_NODES * DIM / 4 + 255) / 256, 256, 0, stream>>>(
        (const float4*)x, (ushort4*)h1, N_NODES * DIM / 4);
    conv_w_kernel<<<512 * 512 / 256, 256, 0, stream>>>(w_self1, wb1);
    conv_w_kernel<<<512 * 512 / 256, 256, 0, stream>>>(w_self2, wb2);
    conv_wexp_kernel<<<(N_REL * 5 * DIM + 255) / 256, 256, 0, stream>>>(w_rel1, wexp1);
    conv_wexp_kernel<<<(N_REL * 5 * DIM + 255) / 256, 256, 0, stream>>>(w_rel2, wexp2);

    // swizzled 1D grid: ceil(782/8)=98 m-locs x 8 xcd x 4 nblk
    const int GB = 98 * 8 * 4;

    // layer 1: out(f32) = x_bf16 @ w_self1 (MFMA); h1 = relu(out + msgs(x_f32)) [bf16]
    gemm_mfma128_kernel<<<GB, 256, 0, stream>>>(h1, wb1, out, N_NODES);
    gather_kernel<false, true><<<N_NODES / 2, 256, 0, stream>>>(
        x, wexp1, elist2, rowptr, out, nullptr, h1);

    // layer 2: out(f32) = h1 @ w_self2 (MFMA); out = relu(out + msgs(h1)) [f32]
    gemm_mfma128_kernel<<<GB, 256, 0, stream>>>(h1, wb2, out, N_NODES);
    gather_kernel<true, false><<<N_NODES / 2, 256, 0, stream>>>(
        h1, wexp2, elist2, rowptr, out, out, nullptr);
}